// Round 7
// baseline (228.586 us; speedup 1.0000x reference)
//
#include <hip/hip_runtime.h>
#include <stdint.h>

// Problem constants
#define BB 2
#define SS 2048
#define DD 1024
#define HH 16
#define DHD 64
#define MM (BB * SS)  // 4096

typedef unsigned short u16;
typedef unsigned int u32;
typedef __attribute__((ext_vector_type(8))) short bhalf8;   // 8 bf16 in 4 VGPRs
typedef __attribute__((ext_vector_type(4))) float floatx4;  // MFMA 16x16 accumulator
typedef __attribute__((ext_vector_type(2))) u32 u32x2;
typedef __attribute__((ext_vector_type(4))) u32 u32x4;
typedef __attribute__((address_space(3))) u32 as3_u32;
typedef __attribute__((address_space(1))) u32 as1_u32;

__device__ __forceinline__ u16 f2bf(float f) {
  u32 u = __float_as_uint(f);
  u32 r = (u + 0x7FFFu + ((u >> 16) & 1u)) >> 16;  // RNE
  return (u16)r;
}

__device__ __forceinline__ u32 cvtpk_bf16(float lo, float hi) {
  u32 r;
  asm("v_cvt_pk_bf16_f32 %0, %1, %2" : "=v"(r) : "v"(lo), "v"(hi));
  return r;
}

__device__ __forceinline__ float exp2_fast(float x) {  // v_exp_f32 computes 2^x
  float r;
  asm("v_exp_f32 %0, %1" : "=v"(r) : "v"(x));
  return r;
}

// async global->LDS, 16B per lane; lds dest must be wave-uniform base (+lane*16 by HW)
__device__ __forceinline__ void gload16(const void* g, const void* l) {
  __builtin_amdgcn_global_load_lds((as1_u32*)(uintptr_t)g, (as3_u32*)(uintptr_t)l, 16, 0, 0);
}

// ---------------- fused W[K][N] fp32 -> Wt[N][K] bf16 (z-indexed, scaled) ----------
// z==0 (Wq) folds 1/sqrt(DH) * log2(e) so attention scores come out in log2 units.
__global__ void k_transpose4(const float* __restrict__ Wq, const float* __restrict__ Wk,
                             const float* __restrict__ Wv, const float* __restrict__ Wo,
                             u16* __restrict__ Wt) {
  const int z = blockIdx.z;
  const float* W = (z == 0) ? Wq : (z == 1) ? Wk : (z == 2) ? Wv : Wo;
  const float sc = (z == 0) ? 0.18033688011112042f : 1.0f;  // 0.125 * log2(e)
  __shared__ u16 tile[32][33];
  const int tx = threadIdx.x, ty = threadIdx.y;  // (32, 8)
  const int n0 = blockIdx.x * 32, k0 = blockIdx.y * 32;
#pragma unroll
  for (int i = 0; i < 4; ++i)
    tile[ty + 8 * i][tx] = f2bf(W[(size_t)(k0 + ty + 8 * i) * DD + n0 + tx] * sc);
  __syncthreads();
  u16* dst = Wt + (size_t)z * 1048576;
#pragma unroll
  for (int i = 0; i < 4; ++i)
    dst[(size_t)(n0 + ty + 8 * i) * DD + k0 + tx] = tile[tx][ty + 8 * i];
}

// ---------------- fused QKV GEMM, convert folded in: A read as fp32 ------------------
// 1D grid 768, XCD-swizzled (8 col-blocks of one (row,z) group share id%8 -> one XCD).
// A staged as fp32 into XOR-swizzled LDS (pre-swizzled global source, rule #21);
// fragments converted fp32->bf16 in-register via v_cvt_pk_bf16_f32.
__global__ __launch_bounds__(256, 2) void k_gemm_qkv(
    const float* __restrict__ Xq, const float* __restrict__ Xk, const float* __restrict__ Xv,
    const u16* __restrict__ Wt, u16* __restrict__ Qb, u16* __restrict__ Kb,
    u16* __restrict__ Vtb) {
  const int id = blockIdx.x;
  const int rr = id & 7, t8 = id >> 3;
  const int g = (t8 >> 3) * 8 + rr, c = t8 & 7;  // g in [0,96), c in [0,8)
  const int z = g / 32, by = g % 32, bx = c;
  const float* A = (z == 0) ? Xq : (z == 1) ? Xk : Xv;
  const u16* Bt = Wt + (size_t)z * 1048576;
  __shared__ __attribute__((aligned(16))) float sAf[2][128 * 32];  // fp32, swizzled
  __shared__ __attribute__((aligned(16))) u16 sB[2][128 * 32];
  const int t = threadIdx.x;
  const int w = t >> 6, lane = t & 63;
  const int lr = lane & 15, lg = lane >> 4;
  const int wr = w >> 1, wc = w & 1;
  const int row0 = by * 128, col0 = bx * 128;

  // A staging: unit u = w*64 + j*256 + lane (16B units); row = u>>3, dest col16 = u&7,
  // source col16 = (lane&7)^(lane>>3)  (both-sides swizzle)
  const int scol16 = (lane & 7) ^ (lane >> 3);
  const float* gA0 = A + (size_t)(row0 + w * 8 + (lane >> 3)) * DD + scol16 * 4;
  // B staging (bf16 rows, linear)
  const int srowB = t >> 2;
  const int skoffB = (t & 3) * 8;
  const u16* gB = Bt + (size_t)(col0 + srowB) * DD + skoffB;
  const int ldsbaseB = w * 512;

  floatx4 acc[4][4] = {};

  auto stage = [&](int buf, int kt) {
    const int ko = kt * 32;
#pragma unroll
    for (int j = 0; j < 4; ++j)
      gload16(gA0 + (size_t)j * 32 * DD + ko, &sAf[buf][w * 256 + j * 1024]);
    gload16(gB + ko, &sB[buf][ldsbaseB]);
    gload16(gB + ko + (size_t)64 * DD, &sB[buf][2048 + ldsbaseB]);
  };

  const int swz = lr & 7;  // row&7 of fragment rows (rows are +16 apart)
  int cur = 0;
  stage(0, 0);
  __syncthreads();
  for (int kt = 0; kt < 32; ++kt) {
    if (kt + 1 < 32) stage(cur ^ 1, kt + 1);
    bhalf8 af[4], bf[4];
#pragma unroll
    for (int m = 0; m < 4; ++m) {
      const int r = wr * 64 + m * 16 + lr;
      const float4 a0 = *(const float4*)&sAf[cur][(r * 8 + ((lg * 2) ^ swz)) * 4];
      const float4 a1 = *(const float4*)&sAf[cur][(r * 8 + ((lg * 2 + 1) ^ swz)) * 4];
      u32x4 pk;
      pk.x = cvtpk_bf16(a0.x, a0.y); pk.y = cvtpk_bf16(a0.z, a0.w);
      pk.z = cvtpk_bf16(a1.x, a1.y); pk.w = cvtpk_bf16(a1.z, a1.w);
      af[m] = __builtin_bit_cast(bhalf8, pk);
    }
#pragma unroll
    for (int n = 0; n < 4; ++n)
      bf[n] = *(const bhalf8*)&sB[cur][(wc * 64 + n * 16 + lr) * 32 + lg * 8];
#pragma unroll
    for (int m = 0; m < 4; ++m)
#pragma unroll
      for (int n = 0; n < 4; ++n)
        acc[m][n] = __builtin_amdgcn_mfma_f32_16x16x32_bf16(af[m], bf[n], acc[m][n], 0, 0, 0);
    __syncthreads();
    cur ^= 1;
  }

#pragma unroll
  for (int m = 0; m < 4; ++m) {
#pragma unroll
    for (int n = 0; n < 4; ++n) {
      const int col = col0 + wc * 64 + n * 16 + lr;
      const int rowb = row0 + wr * 64 + m * 16 + lg * 4;
      if (z == 2) {
        // V^T layout: Vtb[(b*1024 + col)][s]
        const int bidx = rowb >> 11, s = rowb & (SS - 1);
        ushort4 pk;
        pk.x = f2bf(acc[m][n][0]); pk.y = f2bf(acc[m][n][1]);
        pk.z = f2bf(acc[m][n][2]); pk.w = f2bf(acc[m][n][3]);
        *(ushort4*)&Vtb[((size_t)bidx * 1024 + col) * SS + s] = pk;
      } else {
        u16* C = (z == 0) ? Qb : Kb;
#pragma unroll
        for (int r = 0; r < 4; ++r)
          C[(size_t)(rowb + r) * DD + col] = f2bf(acc[m][n][r]);
      }
    }
  }
}

// ---------------- Wo GEMM with fused split-KV merge --------------------------------
// 1D grid 512, XCD-swizzled; 64x128 tile, fp32 out. A-tile is built per K-step by
// reg-loading both fp32 partials + (m,l), merging/normalizing in-register, and
// ds_write_b128 of the bf16 tile (issue-early loads hide under MFMA phase).
template <int P>
__global__ __launch_bounds__(256, 2) void k_gemm_wo(
    const float* __restrict__ Opart, const float2* __restrict__ Ml,
    const int* __restrict__ valid_lens, const u16* __restrict__ Bt,
    float* __restrict__ C) {
  const int id = blockIdx.x;
  const int rr = id & 7, t8 = id >> 3;
  const int g = (t8 >> 3) * 8 + rr, c = t8 & 7;  // g rows, c cols
  const int by = g, bx = c;
  __shared__ __attribute__((aligned(16))) u16 sA[2][64 * 32];
  __shared__ __attribute__((aligned(16))) u16 sB[2][128 * 32];
  const int t = threadIdx.x;
  const int w = t >> 6, lane = t & 63;
  const int lr = lane & 15, lg = lane >> 4;
  const int wr = w >> 1, wc = w & 1;
  const int row0 = by * 64, col0 = bx * 128;

  // merged-A staging: thread covers row arow, 8 dims at dcol
  const int arow = t >> 2;
  const int R = row0 + arow;
  const int bb = R >> 11, s = R & (SS - 1);
  const int dcol = (t & 3) * 8;
  const bool live1 = (P == 2) && (valid_lens[bb] > SS / P);
  constexpr size_t PSTRIDE = (size_t)BB * HH * SS;  // rows per partition

  const int srowB = t >> 2;
  const int skoffB = (t & 3) * 8;
  const u16* gB = Bt + (size_t)(col0 + srowB) * DD + skoffB;
  const int ldsbaseB = w * 512;

  floatx4 acc[2][4] = {};
  float4 x0, x1, y0, y1;
  float w0, w1;

  auto loadA = [&](int kt) {
    const int hh = kt >> 1, d0 = (kt & 1) * 32 + dcol;
    const size_t rbase = (size_t)(bb * HH + hh) * SS + s;
    x0 = *(const float4*)&Opart[rbase * DHD + d0];
    x1 = *(const float4*)&Opart[rbase * DHD + d0 + 4];
    const float2 ml0 = Ml[rbase];
    float L;
    if (live1) {
      const float2 ml1 = Ml[PSTRIDE + rbase];
      y0 = *(const float4*)&Opart[(PSTRIDE + rbase) * DHD + d0];
      y1 = *(const float4*)&Opart[(PSTRIDE + rbase) * DHD + d0 + 4];
      const float M = fmaxf(ml0.x, ml1.x);
      w0 = exp2_fast(ml0.x - M);
      w1 = exp2_fast(ml1.x - M);
      L = ml0.y * w0 + ml1.y * w1;
    } else {
      w0 = 1.f; w1 = 0.f;
      L = ml0.y;
    }
    const float inv = 1.0f / L;
    w0 *= inv; w1 *= inv;
  };

  auto writeA = [&](int buf) {
    float f0 = x0.x * w0, f1 = x0.y * w0, f2 = x0.z * w0, f3 = x0.w * w0;
    float f4 = x1.x * w0, f5 = x1.y * w0, f6 = x1.z * w0, f7 = x1.w * w0;
    if (live1) {
      f0 += y0.x * w1; f1 += y0.y * w1; f2 += y0.z * w1; f3 += y0.w * w1;
      f4 += y1.x * w1; f5 += y1.y * w1; f6 += y1.z * w1; f7 += y1.w * w1;
    }
    u32x4 pk;
    pk.x = cvtpk_bf16(f0, f1); pk.y = cvtpk_bf16(f2, f3);
    pk.z = cvtpk_bf16(f4, f5); pk.w = cvtpk_bf16(f6, f7);
    *(u32x4*)&sA[buf][arow * 32 + (t & 3) * 8] = pk;
  };

  auto stageB = [&](int buf, int kt) {
    const int ko = kt * 32;
    gload16(gB + ko, &sB[buf][ldsbaseB]);
    gload16(gB + ko + (size_t)64 * DD, &sB[buf][2048 + ldsbaseB]);
  };

  // prologue
  loadA(0);
  stageB(0, 0);
  writeA(0);
  __syncthreads();

  int cur = 0;
  for (int kt = 0; kt < 32; ++kt) {
    if (kt + 1 < 32) {
      stageB(cur ^ 1, kt + 1);
      loadA(kt + 1);  // issue early; consumed by writeA after compute
    }
    bhalf8 af[2], bf[4];
#pragma unroll
    for (int m = 0; m < 2; ++m)
      af[m] = *(const bhalf8*)&sA[cur][(wr * 32 + m * 16 + lr) * 32 + lg * 8];
#pragma unroll
    for (int n = 0; n < 4; ++n)
      bf[n] = *(const bhalf8*)&sB[cur][(wc * 64 + n * 16 + lr) * 32 + lg * 8];
#pragma unroll
    for (int m = 0; m < 2; ++m)
#pragma unroll
      for (int n = 0; n < 4; ++n)
        acc[m][n] = __builtin_amdgcn_mfma_f32_16x16x32_bf16(af[m], bf[n], acc[m][n], 0, 0, 0);
    if (kt + 1 < 32) writeA(cur ^ 1);
    __syncthreads();
    cur ^= 1;
  }

#pragma unroll
  for (int m = 0; m < 2; ++m)
#pragma unroll
    for (int n = 0; n < 4; ++n) {
      const int col = col0 + wc * 64 + n * 16 + lr;
      const int rowb = row0 + wr * 32 + m * 16 + lg * 4;
#pragma unroll
      for (int r = 0; r < 4; ++r)
        C[(size_t)(rowb + r) * DD + col] = acc[m][n][r];
    }
}

// ---------------- flash attention (LDS K/V, split-KV, XCD-swizzled grid) -------------
// 1D grid 1024*P, 256 threads = 4 waves, each wave owns 16 q-rows, KV tile = 64.
__global__ __launch_bounds__(256, 2) void k_attn(
    const u16* __restrict__ Q, const u16* __restrict__ K, const u16* __restrict__ Vt,
    float* __restrict__ Opart, float2* __restrict__ Ml,
    const int* __restrict__ valid_lens, const int part) {
  const int id = blockIdx.x;
  const int rr = id & 7, tt = id >> 3;
  const int g = (tt >> 5) * 8 + rr, c = tt & 31;  // g = zi*16 + h
  const int h = g & 15, zi = g >> 4;
  const int b = zi & 1, p = zi >> 1;
  const int t = threadIdx.x;
  const int w = t >> 6, lane = t & 63;
  const int lr = lane & 15, lg = lane >> 4;
  const int q0 = c * 64 + w * 16;
  const int vl = valid_lens[b];
  const int kbeg = p * part;
  if (kbeg >= vl) return;  // dead partition (uniform)
  const int kend = (vl < kbeg + part) ? vl : (kbeg + part);
  const int L = kend - kbeg;

  __shared__ __attribute__((aligned(16))) u16 kbuf[2][64 * 64];  // [key][dim] swizzled
  __shared__ __attribute__((aligned(16))) u16 vbuf[2][64 * 64];  // [d][key]  swizzled
  __shared__ __attribute__((aligned(16))) u16 p_lds[4][16 * 72]; // wave-private
  u16* pl = &p_lds[w][0];

  const u16* Qp = Q + ((size_t)(b * SS + q0 + lr)) * DD + h * DHD;
  const bhalf8 qf0 = *(const bhalf8*)(Qp + lg * 8);
  const bhalf8 qf1 = *(const bhalf8*)(Qp + 32 + lg * 8);

  // staging source (per-lane, pre-swizzled so linear LDS dest ends up swizzled)
  const int sub = lane >> 3;          // row-in-octet 0..7 (== row&7 of dest row)
  const int sc16 = (lane & 7) ^ sub;  // swizzled source col16
  const u16* ksrc = K + (size_t)(b * SS + kbeg + w * 16 + sub) * DD + h * DHD + sc16 * 8;
  const u16* vsrc = Vt + ((size_t)(b * HH + h) * DHD + w * 16 + sub) * SS + kbeg + sc16 * 8;

  auto stage = [&](int buf, int i) {
    const int sk0 = i * 64;
    gload16(ksrc + (size_t)sk0 * DD,       &kbuf[buf][(w * 16) * 64]);
    gload16(ksrc + (size_t)(sk0 + 8) * DD, &kbuf[buf][(w * 16 + 8) * 64]);
    gload16(vsrc + sk0,                    &vbuf[buf][(w * 16) * 64]);
    gload16(vsrc + (size_t)8 * SS + sk0,   &vbuf[buf][(w * 16 + 8) * 64]);
  };

  float mrun = -1e30f, lrun = 0.f;  // per-lane: stats of q-row (q0 + lr), log2 units
  floatx4 o[4] = {};                // o[dt]: C[q = lg*4+r][d = dt*16+lr]

  const int nblk = (L + 63) >> 6;
  const bool partial = (L & 63) != 0;
  const int swz = lr & 7;  // fragment-read swizzle (row&7 for rows c*16+lr / dt*16+lr)

  stage(0, 0);
  __syncthreads();

  int cb = 0;
  for (int i = 0; i < nblk; ++i) {
    if (i + 1 < nblk) stage(cb ^ 1, i + 1);
    const u16* kb = &kbuf[cb][0];
    const u16* vb = &vbuf[cb][0];
    // QK^T from LDS K-frags
    floatx4 s[4];
    __builtin_amdgcn_s_setprio(1);
#pragma unroll
    for (int cc = 0; cc < 4; ++cc) {
      const bhalf8 kc0 = *(const bhalf8*)&kb[(cc * 16 + lr) * 64 + ((lg ^ swz) * 8)];
      const bhalf8 kc1 = *(const bhalf8*)&kb[(cc * 16 + lr) * 64 + (((lg + 4) ^ swz) * 8)];
      floatx4 zz = {0.f, 0.f, 0.f, 0.f};
      zz = __builtin_amdgcn_mfma_f32_16x16x32_bf16(kc0, qf0, zz, 0, 0, 0);
      s[cc] = __builtin_amdgcn_mfma_f32_16x16x32_bf16(kc1, qf1, zz, 0, 0, 0);
    }
    __builtin_amdgcn_s_setprio(0);
    // mask tail keys (uniform branch; key index is per-reg)
    if (partial && i == nblk - 1) {
      const int sk0 = i * 64;
#pragma unroll
      for (int cc = 0; cc < 4; ++cc)
#pragma unroll
        for (int r = 0; r < 4; ++r)
          if (sk0 + cc * 16 + lg * 4 + r >= L) s[cc][r] = -1e6f;
    }
    // row max: in-register tree + 2 cross-lane steps
    float tmax = fmaxf(fmaxf(fmaxf(s[0][0], s[0][1]), fmaxf(s[0][2], s[0][3])),
                       fmaxf(fmaxf(s[1][0], s[1][1]), fmaxf(s[1][2], s[1][3])));
    tmax = fmaxf(tmax, fmaxf(fmaxf(fmaxf(s[2][0], s[2][1]), fmaxf(s[2][2], s[2][3])),
                             fmaxf(fmaxf(s[3][0], s[3][1]), fmaxf(s[3][2], s[3][3]))));
    tmax = fmaxf(tmax, __shfl_xor(tmax, 16));
    tmax = fmaxf(tmax, __shfl_xor(tmax, 32));
    // defer-max: skip O-rescale while max growth <= 8 (log2 units; P bounded by 256)
    if (!__all(tmax <= mrun + 8.0f)) {
      const float nm = fmaxf(mrun, tmax);
      const float sc = exp2_fast(mrun - nm);
      mrun = nm;
      lrun *= sc;
      float scb[4];
#pragma unroll
      for (int r = 0; r < 4; ++r) scb[r] = __shfl(sc, lg * 4 + r);
#pragma unroll
      for (int dt = 0; dt < 4; ++dt)
#pragma unroll
        for (int r = 0; r < 4; ++r) o[dt][r] *= scb[r];
    }
    // p = exp2(s - m), row sum, pack to bf16 pairs
    float rs = 0.f;
    u32 pk[4][2];
#pragma unroll
    for (int cc = 0; cc < 4; ++cc) {
      float p0 = exp2_fast(s[cc][0] - mrun), p1 = exp2_fast(s[cc][1] - mrun);
      float p2 = exp2_fast(s[cc][2] - mrun), p3 = exp2_fast(s[cc][3] - mrun);
      rs += (p0 + p1) + (p2 + p3);
      pk[cc][0] = cvtpk_bf16(p0, p1);
      pk[cc][1] = cvtpk_bf16(p2, p3);
    }
    rs += __shfl_xor(rs, 16);
    rs += __shfl_xor(rs, 32);
    lrun += rs;
    // P -> wave-private LDS: lane writes its own q-row (lr)
#pragma unroll
    for (int cc = 0; cc < 4; ++cc) {
      u32x2 pr; pr.x = pk[cc][0]; pr.y = pk[cc][1];
      *(u32x2*)&pl[lr * 72 + cc * 16 + lg * 4] = pr;
    }
    asm volatile("s_waitcnt lgkmcnt(0)" ::: "memory");  // in-wave write->read ordering
    const bhalf8 pa0 = *(const bhalf8*)&pl[lr * 72 + lg * 8];
    const bhalf8 pa1 = *(const bhalf8*)&pl[lr * 72 + 32 + lg * 8];
    // PV from LDS V-frags
    __builtin_amdgcn_s_setprio(1);
#pragma unroll
    for (int dt = 0; dt < 4; ++dt) {
      const bhalf8 vf0 = *(const bhalf8*)&vb[(dt * 16 + lr) * 64 + ((lg ^ swz) * 8)];
      const bhalf8 vf1 = *(const bhalf8*)&vb[(dt * 16 + lr) * 64 + (((lg + 4) ^ swz) * 8)];
      o[dt] = __builtin_amdgcn_mfma_f32_16x16x32_bf16(pa0, vf0, o[dt], 0, 0, 0);
      o[dt] = __builtin_amdgcn_mfma_f32_16x16x32_bf16(pa1, vf1, o[dt], 0, 0, 0);
    }
    __builtin_amdgcn_s_setprio(0);
    __syncthreads();  // staging of next tile drained + all waves done with cb
    cb ^= 1;
  }

  // epilogue: store unnormalized partial + (m, l)
  const size_t rowbase = ((size_t)(b * HH + h)) * SS + q0;
  const size_t pbase = (size_t)p * (BB * HH * SS);
#pragma unroll
  for (int dt = 0; dt < 4; ++dt)
#pragma unroll
    for (int r = 0; r < 4; ++r)
      Opart[(pbase + rowbase + lg * 4 + r) * DHD + dt * 16 + lr] = o[dt][r];
  if (lane < 16) {
    float2 ml; ml.x = mrun; ml.y = lrun;
    Ml[pbase + rowbase + lr] = ml;
  }
}

extern "C" void kernel_launch(void* const* d_in, const int* in_sizes, int n_in,
                              void* d_out, int out_size, void* d_ws, size_t ws_size,
                              hipStream_t stream) {
  const float* q = (const float*)d_in[0];
  const float* k = (const float*)d_in[1];
  const float* v = (const float*)d_in[2];
  const int* vl = (const int*)d_in[3];
  const float* Wq = (const float*)d_in[4];
  const float* Wk = (const float*)d_in[5];
  const float* Wv = (const float*)d_in[6];
  const float* Wo = (const float*)d_in[7];

  char* ws = (char*)d_ws;
  u16* Wt  = (u16*)(ws + 0);          // 4 x 2 MiB (Wq,Wk,Wv,Wo transposed bf16)
  u16* Qb  = (u16*)(ws + 8388608);    // 8 MiB each
  u16* Kb  = (u16*)(ws + 16777216);
  u16* Vtb = (u16*)(ws + 25165824);
  float* Opart = (float*)(ws + 33554432);  // P x 16 MiB fp32 partials

  const bool big = ws_size >= (size_t)134 * 1024 * 1024;
  const int P = big ? 2 : 1;
  const int part = SS / P;
  float2* Ml = big ? (float2*)(ws + 67108864) : (float2*)(ws + 50331648);

  k_transpose4<<<dim3(32, 32, 4), dim3(32, 8), 0, stream>>>(Wq, Wk, Wv, Wo, Wt);
  k_gemm_qkv<<<768, 256, 0, stream>>>(q, k, v, Wt, Qb, Kb, Vtb);
  k_attn<<<1024 * P, 256, 0, stream>>>(Qb, Kb, Vtb, Opart, Ml, vl, part);
  u16* Wto = Wt + 3 * 1048576;
  if (big) k_gemm_wo<2><<<512, 256, 0, stream>>>(Opart, Ml, vl, Wto, (float*)d_out);
  else     k_gemm_wo<1><<<512, 256, 0, stream>>>(Opart, Ml, vl, Wto, (float*)d_out);
}

// Round 8
// 219.505 us; speedup vs baseline: 1.0414x; 1.0414x over previous
//
#include <hip/hip_runtime.h>
#include <stdint.h>

// Problem constants
#define BB 2
#define SS 2048
#define DD 1024
#define HH 16
#define DHD 64
#define MM (BB * SS)  // 4096

typedef unsigned short u16;
typedef unsigned int u32;
typedef __attribute__((ext_vector_type(8))) short bhalf8;   // 8 bf16 in 4 VGPRs
typedef __attribute__((ext_vector_type(4))) float floatx4;  // MFMA 16x16 accumulator
typedef __attribute__((ext_vector_type(2))) u32 u32x2;
typedef __attribute__((ext_vector_type(4))) u32 u32x4;
typedef __attribute__((address_space(3))) u32 as3_u32;
typedef __attribute__((address_space(1))) u32 as1_u32;

__device__ __forceinline__ u16 f2bf(float f) {
  u32 u = __float_as_uint(f);
  u32 r = (u + 0x7FFFu + ((u >> 16) & 1u)) >> 16;  // RNE
  return (u16)r;
}

__device__ __forceinline__ u32 cvtpk_bf16(float lo, float hi) {
  u32 r;
  asm("v_cvt_pk_bf16_f32 %0, %1, %2" : "=v"(r) : "v"(lo), "v"(hi));
  return r;
}

__device__ __forceinline__ float exp2_fast(float x) {  // v_exp_f32 computes 2^x
  float r;
  asm("v_exp_f32 %0, %1" : "=v"(r) : "v"(x));
  return r;
}

// async global->LDS, 16B per lane; lds dest must be wave-uniform base (+lane*16 by HW)
__device__ __forceinline__ void gload16(const void* g, const void* l) {
  __builtin_amdgcn_global_load_lds((as1_u32*)(uintptr_t)g, (as3_u32*)(uintptr_t)l, 16, 0, 0);
}

// ---------------- fused fp32 -> bf16 convert for q,k,v (z-indexed) ----------------
__global__ void k_convert3(const float* __restrict__ q, const float* __restrict__ k,
                           const float* __restrict__ v, u16* __restrict__ out) {
  const int z = blockIdx.y;
  const float* src = (z == 0) ? q : (z == 1) ? k : v;
  const int i = blockIdx.x * 256 + threadIdx.x;  // grid.x*256 == 4M/4 exactly
  float4 val = ((const float4*)src)[i];
  ushort4 o;
  o.x = f2bf(val.x); o.y = f2bf(val.y); o.z = f2bf(val.z); o.w = f2bf(val.w);
  ((ushort4*)(out + (size_t)z * 4194304))[i] = o;
}

// ---------------- fused W[K][N] fp32 -> Wt[N][K] bf16 (z-indexed, scaled) ----------
// z==0 (Wq) folds 1/sqrt(DH) * log2(e) so attention scores come out in log2 units.
__global__ void k_transpose4(const float* __restrict__ Wq, const float* __restrict__ Wk,
                             const float* __restrict__ Wv, const float* __restrict__ Wo,
                             u16* __restrict__ Wt) {
  const int z = blockIdx.z;
  const float* W = (z == 0) ? Wq : (z == 1) ? Wk : (z == 2) ? Wv : Wo;
  const float sc = (z == 0) ? 0.18033688011112042f : 1.0f;  // 0.125 * log2(e)
  __shared__ u16 tile[32][33];
  const int tx = threadIdx.x, ty = threadIdx.y;  // (32, 8)
  const int n0 = blockIdx.x * 32, k0 = blockIdx.y * 32;
#pragma unroll
  for (int i = 0; i < 4; ++i)
    tile[ty + 8 * i][tx] = f2bf(W[(size_t)(k0 + ty + 8 * i) * DD + n0 + tx] * sc);
  __syncthreads();
  u16* dst = Wt + (size_t)z * 1048576;
#pragma unroll
  for (int i = 0; i < 4; ++i)
    dst[(size_t)(n0 + ty + 8 * i) * DD + k0 + tx] = tile[tx][ty + 8 * i];
}

// ---------------- fused QKV GEMM: 1D grid 768, XCD-swizzled; 128x128 tile, BK=32 -----
// id = r + 8*(a*8 + c): the 8 col-blocks (c) of group g=8a+r share id%8 -> same XCD,
// so each A row-panel is fetched into one XCD's L2 instead of all eight.
__global__ __launch_bounds__(256, 2) void k_gemm_qkv(
    const u16* __restrict__ Xq, const u16* __restrict__ Xk, const u16* __restrict__ Xv,
    const u16* __restrict__ Wt, u16* __restrict__ Qb, u16* __restrict__ Kb,
    u16* __restrict__ Vtb) {
  const int id = blockIdx.x;
  const int rr = id & 7, t8 = id >> 3;
  const int g = (t8 >> 3) * 8 + rr, c = t8 & 7;  // g in [0,96), c in [0,8)
  const int z = g / 32, by = g % 32, bx = c;
  const u16* A = (z == 0) ? Xq : (z == 1) ? Xk : Xv;
  const u16* Bt = Wt + (size_t)z * 1048576;
  __shared__ __attribute__((aligned(16))) u16 sA[2][128 * 32];
  __shared__ __attribute__((aligned(16))) u16 sB[2][128 * 32];
  const int t = threadIdx.x;
  const int w = t >> 6, lane = t & 63;
  const int lr = lane & 15, lg = lane >> 4;
  const int wr = w >> 1, wc = w & 1;
  const int row0 = by * 128, col0 = bx * 128;

  const int srow = t >> 2;
  const int skoff = (t & 3) * 8;
  const u16* gA = A + (size_t)(row0 + srow) * DD + skoff;
  const u16* gB = Bt + (size_t)(col0 + srow) * DD + skoff;
  const int ldsbase = w * 512;

  floatx4 acc[4][4] = {};

  auto stage = [&](int buf, int kt) {
    const int ko = kt * 32;
    gload16(gA + ko, &sA[buf][ldsbase]);
    gload16(gA + ko + (size_t)64 * DD, &sA[buf][2048 + ldsbase]);
    gload16(gB + ko, &sB[buf][ldsbase]);
    gload16(gB + ko + (size_t)64 * DD, &sB[buf][2048 + ldsbase]);
  };

  int cur = 0;
  stage(0, 0);
  __syncthreads();
  for (int kt = 0; kt < 32; ++kt) {
    if (kt + 1 < 32) stage(cur ^ 1, kt + 1);
    bhalf8 af[4], bf[4];
#pragma unroll
    for (int m = 0; m < 4; ++m)
      af[m] = *(const bhalf8*)&sA[cur][(wr * 64 + m * 16 + lr) * 32 + lg * 8];
#pragma unroll
    for (int n = 0; n < 4; ++n)
      bf[n] = *(const bhalf8*)&sB[cur][(wc * 64 + n * 16 + lr) * 32 + lg * 8];
#pragma unroll
    for (int m = 0; m < 4; ++m)
#pragma unroll
      for (int n = 0; n < 4; ++n)
        acc[m][n] = __builtin_amdgcn_mfma_f32_16x16x32_bf16(af[m], bf[n], acc[m][n], 0, 0, 0);
    __syncthreads();
    cur ^= 1;
  }

#pragma unroll
  for (int m = 0; m < 4; ++m) {
#pragma unroll
    for (int n = 0; n < 4; ++n) {
      const int col = col0 + wc * 64 + n * 16 + lr;
      const int rowb = row0 + wr * 64 + m * 16 + lg * 4;
      if (z == 2) {
        // V^T layout: Vtb[(b*1024 + col)][s]
        const int bidx = rowb >> 11, s = rowb & (SS - 1);
        ushort4 pk;
        pk.x = f2bf(acc[m][n][0]); pk.y = f2bf(acc[m][n][1]);
        pk.z = f2bf(acc[m][n][2]); pk.w = f2bf(acc[m][n][3]);
        *(ushort4*)&Vtb[((size_t)bidx * 1024 + col) * SS + s] = pk;
      } else {
        u16* C = (z == 0) ? Qb : Kb;
#pragma unroll
        for (int r = 0; r < 4; ++r)
          C[(size_t)(rowb + r) * DD + col] = f2bf(acc[m][n][r]);
      }
    }
  }
}

// ---------------- Wo GEMM with fused split-KV merge --------------------------------
// 1D grid 512, XCD-swizzled; 64x128 tile, fp32 out. A-tile built per K-step by
// reg-loading both fp32 partials + (m,l), merging/normalizing in-register, then
// ds_write_b128 of the bf16 tile (issue-early loads hide under MFMA phase).
template <int P>
__global__ __launch_bounds__(256, 2) void k_gemm_wo(
    const float* __restrict__ Opart, const float2* __restrict__ Ml,
    const int* __restrict__ valid_lens, const u16* __restrict__ Bt,
    float* __restrict__ C) {
  const int id = blockIdx.x;
  const int rr = id & 7, t8 = id >> 3;
  const int g = (t8 >> 3) * 8 + rr, c = t8 & 7;  // g rows, c cols
  const int by = g, bx = c;
  __shared__ __attribute__((aligned(16))) u16 sA[2][64 * 32];
  __shared__ __attribute__((aligned(16))) u16 sB[2][128 * 32];
  const int t = threadIdx.x;
  const int w = t >> 6, lane = t & 63;
  const int lr = lane & 15, lg = lane >> 4;
  const int wr = w >> 1, wc = w & 1;
  const int row0 = by * 64, col0 = bx * 128;

  // merged-A staging: thread covers row arow, 8 dims at dcol
  const int arow = t >> 2;
  const int R = row0 + arow;
  const int bb = R >> 11, s = R & (SS - 1);
  const int dcol = (t & 3) * 8;
  const bool live1 = (P == 2) && (valid_lens[bb] > SS / P);
  constexpr size_t PSTRIDE = (size_t)BB * HH * SS;  // rows per partition

  const int srowB = t >> 2;
  const int skoffB = (t & 3) * 8;
  const u16* gB = Bt + (size_t)(col0 + srowB) * DD + skoffB;
  const int ldsbaseB = w * 512;

  floatx4 acc[2][4] = {};
  float4 x0, x1, y0, y1;
  float w0, w1;

  auto loadA = [&](int kt) {
    const int hh = kt >> 1, d0 = (kt & 1) * 32 + dcol;
    const size_t rbase = (size_t)(bb * HH + hh) * SS + s;
    x0 = *(const float4*)&Opart[rbase * DHD + d0];
    x1 = *(const float4*)&Opart[rbase * DHD + d0 + 4];
    const float2 ml0 = Ml[rbase];
    float L;
    if (live1) {
      const float2 ml1 = Ml[PSTRIDE + rbase];
      y0 = *(const float4*)&Opart[(PSTRIDE + rbase) * DHD + d0];
      y1 = *(const float4*)&Opart[(PSTRIDE + rbase) * DHD + d0 + 4];
      const float M = fmaxf(ml0.x, ml1.x);
      w0 = exp2_fast(ml0.x - M);
      w1 = exp2_fast(ml1.x - M);
      L = ml0.y * w0 + ml1.y * w1;
    } else {
      w0 = 1.f; w1 = 0.f;
      L = ml0.y;
    }
    const float inv = 1.0f / L;
    w0 *= inv; w1 *= inv;
  };

  auto writeA = [&](int buf) {
    float f0 = x0.x * w0, f1 = x0.y * w0, f2 = x0.z * w0, f3 = x0.w * w0;
    float f4 = x1.x * w0, f5 = x1.y * w0, f6 = x1.z * w0, f7 = x1.w * w0;
    if (live1) {
      f0 += y0.x * w1; f1 += y0.y * w1; f2 += y0.z * w1; f3 += y0.w * w1;
      f4 += y1.x * w1; f5 += y1.y * w1; f6 += y1.z * w1; f7 += y1.w * w1;
    }
    u32x4 pk;
    pk.x = cvtpk_bf16(f0, f1); pk.y = cvtpk_bf16(f2, f3);
    pk.z = cvtpk_bf16(f4, f5); pk.w = cvtpk_bf16(f6, f7);
    *(u32x4*)&sA[buf][arow * 32 + (t & 3) * 8] = pk;
  };

  auto stageB = [&](int buf, int kt) {
    const int ko = kt * 32;
    gload16(gB + ko, &sB[buf][ldsbaseB]);
    gload16(gB + ko + (size_t)64 * DD, &sB[buf][2048 + ldsbaseB]);
  };

  // prologue
  loadA(0);
  stageB(0, 0);
  writeA(0);
  __syncthreads();

  int cur = 0;
  for (int kt = 0; kt < 32; ++kt) {
    if (kt + 1 < 32) {
      stageB(cur ^ 1, kt + 1);
      loadA(kt + 1);  // issue early; consumed by writeA after compute
    }
    bhalf8 af[2], bf[4];
#pragma unroll
    for (int m = 0; m < 2; ++m)
      af[m] = *(const bhalf8*)&sA[cur][(wr * 32 + m * 16 + lr) * 32 + lg * 8];
#pragma unroll
    for (int n = 0; n < 4; ++n)
      bf[n] = *(const bhalf8*)&sB[cur][(wc * 64 + n * 16 + lr) * 32 + lg * 8];
#pragma unroll
    for (int m = 0; m < 2; ++m)
#pragma unroll
      for (int n = 0; n < 4; ++n)
        acc[m][n] = __builtin_amdgcn_mfma_f32_16x16x32_bf16(af[m], bf[n], acc[m][n], 0, 0, 0);
    if (kt + 1 < 32) writeA(cur ^ 1);
    __syncthreads();
    cur ^= 1;
  }

#pragma unroll
  for (int m = 0; m < 2; ++m)
#pragma unroll
    for (int n = 0; n < 4; ++n) {
      const int col = col0 + wc * 64 + n * 16 + lr;
      const int rowb = row0 + wr * 32 + m * 16 + lg * 4;
#pragma unroll
      for (int r = 0; r < 4; ++r)
        C[(size_t)(rowb + r) * DD + col] = acc[m][n][r];
    }
}

// ---------------- flash attention (LDS K/V, split-KV, XCD-swizzled grid) -------------
// 1D grid 1024*P, 256 threads = 4 waves, each wave owns 16 q-rows, KV tile = 64.
// 3 blocks/CU (LDS 41KB x3 = 123KB < 160KB; VGPR 68 << 170).
__global__ __launch_bounds__(256, 3) void k_attn(
    const u16* __restrict__ Q, const u16* __restrict__ K, const u16* __restrict__ Vt,
    float* __restrict__ Opart, float2* __restrict__ Ml,
    const int* __restrict__ valid_lens, const int part) {
  const int id = blockIdx.x;
  const int rr = id & 7, tt = id >> 3;
  const int g = (tt >> 5) * 8 + rr, c = tt & 31;  // g = zi*16 + h
  const int h = g & 15, zi = g >> 4;
  const int b = zi & 1, p = zi >> 1;
  const int t = threadIdx.x;
  const int w = t >> 6, lane = t & 63;
  const int lr = lane & 15, lg = lane >> 4;
  const int q0 = c * 64 + w * 16;
  const int vl = valid_lens[b];
  const int kbeg = p * part;
  if (kbeg >= vl) return;  // dead partition (uniform)
  const int kend = (vl < kbeg + part) ? vl : (kbeg + part);
  const int L = kend - kbeg;

  __shared__ __attribute__((aligned(16))) u16 kbuf[2][64 * 64];  // [key][dim] swizzled
  __shared__ __attribute__((aligned(16))) u16 vbuf[2][64 * 64];  // [d][key]  swizzled
  __shared__ __attribute__((aligned(16))) u16 p_lds[4][16 * 72]; // wave-private
  u16* pl = &p_lds[w][0];

  const u16* Qp = Q + ((size_t)(b * SS + q0 + lr)) * DD + h * DHD;
  const bhalf8 qf0 = *(const bhalf8*)(Qp + lg * 8);
  const bhalf8 qf1 = *(const bhalf8*)(Qp + 32 + lg * 8);

  // staging source (per-lane, pre-swizzled so linear LDS dest ends up swizzled)
  const int sub = lane >> 3;          // row-in-octet 0..7 (== row&7 of dest row)
  const int sc16 = (lane & 7) ^ sub;  // swizzled source col16
  const u16* ksrc = K + (size_t)(b * SS + kbeg + w * 16 + sub) * DD + h * DHD + sc16 * 8;
  const u16* vsrc = Vt + ((size_t)(b * HH + h) * DHD + w * 16 + sub) * SS + kbeg + sc16 * 8;

  auto stage = [&](int buf, int i) {
    const int sk0 = i * 64;
    gload16(ksrc + (size_t)sk0 * DD,       &kbuf[buf][(w * 16) * 64]);
    gload16(ksrc + (size_t)(sk0 + 8) * DD, &kbuf[buf][(w * 16 + 8) * 64]);
    gload16(vsrc + sk0,                    &vbuf[buf][(w * 16) * 64]);
    gload16(vsrc + (size_t)8 * SS + sk0,   &vbuf[buf][(w * 16 + 8) * 64]);
  };

  float mrun = -1e30f, lrun = 0.f;  // per-lane: stats of q-row (q0 + lr), log2 units
  floatx4 o[4] = {};                // o[dt]: C[q = lg*4+r][d = dt*16+lr]

  const int nblk = (L + 63) >> 6;
  const bool partial = (L & 63) != 0;
  const int swz = lr & 7;  // fragment-read swizzle (row&7 for rows c*16+lr / dt*16+lr)

  stage(0, 0);
  __syncthreads();

  int cb = 0;
  for (int i = 0; i < nblk; ++i) {
    if (i + 1 < nblk) stage(cb ^ 1, i + 1);
    const u16* kb = &kbuf[cb][0];
    const u16* vb = &vbuf[cb][0];
    // QK^T from LDS K-frags
    floatx4 s[4];
    __builtin_amdgcn_s_setprio(1);
#pragma unroll
    for (int cc = 0; cc < 4; ++cc) {
      const bhalf8 kc0 = *(const bhalf8*)&kb[(cc * 16 + lr) * 64 + ((lg ^ swz) * 8)];
      const bhalf8 kc1 = *(const bhalf8*)&kb[(cc * 16 + lr) * 64 + (((lg + 4) ^ swz) * 8)];
      floatx4 zz = {0.f, 0.f, 0.f, 0.f};
      zz = __builtin_amdgcn_mfma_f32_16x16x32_bf16(kc0, qf0, zz, 0, 0, 0);
      s[cc] = __builtin_amdgcn_mfma_f32_16x16x32_bf16(kc1, qf1, zz, 0, 0, 0);
    }
    __builtin_amdgcn_s_setprio(0);
    // mask tail keys (uniform branch; key index is per-reg)
    if (partial && i == nblk - 1) {
      const int sk0 = i * 64;
#pragma unroll
      for (int cc = 0; cc < 4; ++cc)
#pragma unroll
        for (int r = 0; r < 4; ++r)
          if (sk0 + cc * 16 + lg * 4 + r >= L) s[cc][r] = -1e6f;
    }
    // row max: in-register tree + 2 cross-lane steps
    float tmax = fmaxf(fmaxf(fmaxf(s[0][0], s[0][1]), fmaxf(s[0][2], s[0][3])),
                       fmaxf(fmaxf(s[1][0], s[1][1]), fmaxf(s[1][2], s[1][3])));
    tmax = fmaxf(tmax, fmaxf(fmaxf(fmaxf(s[2][0], s[2][1]), fmaxf(s[2][2], s[2][3])),
                             fmaxf(fmaxf(s[3][0], s[3][1]), fmaxf(s[3][2], s[3][3]))));
    tmax = fmaxf(tmax, __shfl_xor(tmax, 16));
    tmax = fmaxf(tmax, __shfl_xor(tmax, 32));
    // defer-max: skip O-rescale while max growth <= 8 (log2 units; P bounded by 256)
    if (!__all(tmax <= mrun + 8.0f)) {
      const float nm = fmaxf(mrun, tmax);
      const float sc = exp2_fast(mrun - nm);
      mrun = nm;
      lrun *= sc;
      float scb[4];
#pragma unroll
      for (int r = 0; r < 4; ++r) scb[r] = __shfl(sc, lg * 4 + r);
#pragma unroll
      for (int dt = 0; dt < 4; ++dt)
#pragma unroll
        for (int r = 0; r < 4; ++r) o[dt][r] *= scb[r];
    }
    // p = exp2(s - m), row sum, pack to bf16 pairs
    float rs = 0.f;
    u32 pk[4][2];
#pragma unroll
    for (int cc = 0; cc < 4; ++cc) {
      float p0 = exp2_fast(s[cc][0] - mrun), p1 = exp2_fast(s[cc][1] - mrun);
      float p2 = exp2_fast(s[cc][2] - mrun), p3 = exp2_fast(s[cc][3] - mrun);
      rs += (p0 + p1) + (p2 + p3);
      pk[cc][0] = cvtpk_bf16(p0, p1);
      pk[cc][1] = cvtpk_bf16(p2, p3);
    }
    rs += __shfl_xor(rs, 16);
    rs += __shfl_xor(rs, 32);
    lrun += rs;
    // P -> wave-private LDS: lane writes its own q-row (lr)
#pragma unroll
    for (int cc = 0; cc < 4; ++cc) {
      u32x2 pr; pr.x = pk[cc][0]; pr.y = pk[cc][1];
      *(u32x2*)&pl[lr * 72 + cc * 16 + lg * 4] = pr;
    }
    asm volatile("s_waitcnt lgkmcnt(0)" ::: "memory");  // in-wave write->read ordering
    const bhalf8 pa0 = *(const bhalf8*)&pl[lr * 72 + lg * 8];
    const bhalf8 pa1 = *(const bhalf8*)&pl[lr * 72 + 32 + lg * 8];
    // PV from LDS V-frags
    __builtin_amdgcn_s_setprio(1);
#pragma unroll
    for (int dt = 0; dt < 4; ++dt) {
      const bhalf8 vf0 = *(const bhalf8*)&vb[(dt * 16 + lr) * 64 + ((lg ^ swz) * 8)];
      const bhalf8 vf1 = *(const bhalf8*)&vb[(dt * 16 + lr) * 64 + (((lg + 4) ^ swz) * 8)];
      o[dt] = __builtin_amdgcn_mfma_f32_16x16x32_bf16(pa0, vf0, o[dt], 0, 0, 0);
      o[dt] = __builtin_amdgcn_mfma_f32_16x16x32_bf16(pa1, vf1, o[dt], 0, 0, 0);
    }
    __builtin_amdgcn_s_setprio(0);
    __syncthreads();  // staging of next tile drained + all waves done with cb
    cb ^= 1;
  }

  // epilogue: store unnormalized partial + (m, l)
  const size_t rowbase = ((size_t)(b * HH + h)) * SS + q0;
  const size_t pbase = (size_t)p * (BB * HH * SS);
#pragma unroll
  for (int dt = 0; dt < 4; ++dt)
#pragma unroll
    for (int r = 0; r < 4; ++r)
      Opart[(pbase + rowbase + lg * 4 + r) * DHD + dt * 16 + lr] = o[dt][r];
  if (lane < 16) {
    float2 ml; ml.x = mrun; ml.y = lrun;
    Ml[pbase + rowbase + lr] = ml;
  }
}

extern "C" void kernel_launch(void* const* d_in, const int* in_sizes, int n_in,
                              void* d_out, int out_size, void* d_ws, size_t ws_size,
                              hipStream_t stream) {
  const float* q = (const float*)d_in[0];
  const float* k = (const float*)d_in[1];
  const float* v = (const float*)d_in[2];
  const int* vl = (const int*)d_in[3];
  const float* Wq = (const float*)d_in[4];
  const float* Wk = (const float*)d_in[5];
  const float* Wv = (const float*)d_in[6];
  const float* Wo = (const float*)d_in[7];

  char* ws = (char*)d_ws;
  u16* Xq  = (u16*)(ws + 0);          // 3 x 8 MiB bf16 inputs (dead after qkv GEMM)
  u16* Wt  = (u16*)(ws + 25165824);   // 4 x 2 MiB transposed weights
  u16* Qb  = (u16*)(ws + 33554432);   // 8 MiB each
  u16* Kb  = (u16*)(ws + 41943040);
  u16* Vtb = (u16*)(ws + 50331648);

  // split-KV partials: P=2 when workspace allows; else P=1 overlaying dead Xq
  const bool big = ws_size >= (size_t)134 * 1024 * 1024;
  const int P = big ? 2 : 1;
  const int part = SS / P;
  float* Opart = big ? (float*)(ws + 67108864) : (float*)(ws + 0);
  float2* Ml   = big ? (float2*)(ws + 100663296) : (float2*)(ws + 16777216);

  k_convert3<<<dim3(4096, 3), 256, 0, stream>>>(q, k, v, Xq);
  k_transpose4<<<dim3(32, 32, 4), dim3(32, 8), 0, stream>>>(Wq, Wk, Wv, Wo, Wt);
  k_gemm_qkv<<<768, 256, 0, stream>>>(Xq, Xq + 4194304, Xq + 8388608, Wt, Qb, Kb, Vtb);
  k_attn<<<1024 * P, 256, 0, stream>>>(Qb, Kb, Vtb, Opart, Ml, vl, part);
  u16* Wto = Wt + 3 * 1048576;
  if (big) k_gemm_wo<2><<<512, 256, 0, stream>>>(Opart, Ml, vl, Wto, (float*)d_out);
  else     k_gemm_wo<1><<<512, 256, 0, stream>>>(Opart, Ml, vl, Wto, (float*)d_out);
}

// Round 9
// 219.489 us; speedup vs baseline: 1.0414x; 1.0001x over previous
//
#include <hip/hip_runtime.h>
#include <stdint.h>

// Problem constants
#define BB 2
#define SS 2048
#define DD 1024
#define HH 16
#define DHD 64
#define MM (BB * SS)  // 4096

typedef unsigned short u16;
typedef unsigned int u32;
typedef __attribute__((ext_vector_type(8))) short bhalf8;   // 8 bf16 in 4 VGPRs
typedef __attribute__((ext_vector_type(4))) float floatx4;  // MFMA 16x16 accumulator
typedef __attribute__((ext_vector_type(2))) u32 u32x2;
typedef __attribute__((ext_vector_type(4))) u32 u32x4;
typedef __attribute__((address_space(3))) u32 as3_u32;
typedef __attribute__((address_space(1))) u32 as1_u32;

__device__ __forceinline__ u16 f2bf(float f) {
  u32 u = __float_as_uint(f);
  u32 r = (u + 0x7FFFu + ((u >> 16) & 1u)) >> 16;  // RNE
  return (u16)r;
}

__device__ __forceinline__ u32 cvtpk_bf16(float lo, float hi) {
  u32 r;
  asm("v_cvt_pk_bf16_f32 %0, %1, %2" : "=v"(r) : "v"(lo), "v"(hi));
  return r;
}

__device__ __forceinline__ float exp2_fast(float x) {  // v_exp_f32 computes 2^x
  float r;
  asm("v_exp_f32 %0, %1" : "=v"(r) : "v"(x));
  return r;
}

// async global->LDS, 16B per lane; lds dest must be wave-uniform base (+lane*16 by HW)
__device__ __forceinline__ void gload16(const void* g, const void* l) {
  __builtin_amdgcn_global_load_lds((as1_u32*)(uintptr_t)g, (as3_u32*)(uintptr_t)l, 16, 0, 0);
}

// ---------------- fused W[K][N] fp32 -> Wt[N][K] bf16 (z-indexed, scaled) ----------
// z==0 (Wq) folds 1/sqrt(DH) * log2(e) so attention scores come out in log2 units.
__global__ void k_transpose4(const float* __restrict__ Wq, const float* __restrict__ Wk,
                             const float* __restrict__ Wv, const float* __restrict__ Wo,
                             u16* __restrict__ Wt) {
  const int z = blockIdx.z;
  const float* W = (z == 0) ? Wq : (z == 1) ? Wk : (z == 2) ? Wv : Wo;
  const float sc = (z == 0) ? 0.18033688011112042f : 1.0f;  // 0.125 * log2(e)
  __shared__ u16 tile[32][33];
  const int tx = threadIdx.x, ty = threadIdx.y;  // (32, 8)
  const int n0 = blockIdx.x * 32, k0 = blockIdx.y * 32;
#pragma unroll
  for (int i = 0; i < 4; ++i)
    tile[ty + 8 * i][tx] = f2bf(W[(size_t)(k0 + ty + 8 * i) * DD + n0 + tx] * sc);
  __syncthreads();
  u16* dst = Wt + (size_t)z * 1048576;
#pragma unroll
  for (int i = 0; i < 4; ++i)
    dst[(size_t)(n0 + ty + 8 * i) * DD + k0 + tx] = tile[tx][ty + 8 * i];
}

// ---------------- fused QKV GEMM with folded fp32->bf16 convert ----------------------
// 1D grid 768, XCD-swizzled. A read as fp32 from the raw inputs, reg-staged (T14:
// loads issued before the MFMA phase, cvt_pk + ds_write after), LDS stays bf16.
// Both A and B tiles use the unit^=(row&3) XOR swizzle (4-way conflicts, was 8-way).
__global__ __launch_bounds__(256, 2) void k_gemm_qkv(
    const float* __restrict__ Xq, const float* __restrict__ Xk, const float* __restrict__ Xv,
    const u16* __restrict__ Wt, u16* __restrict__ Qb, u16* __restrict__ Kb,
    u16* __restrict__ Vtb) {
  const int id = blockIdx.x;
  const int rr = id & 7, t8 = id >> 3;
  const int g = (t8 >> 3) * 8 + rr, c = t8 & 7;  // g in [0,96), c in [0,8)
  const int z = g / 32, by = g % 32, bx = c;
  const float* A = (z == 0) ? Xq : (z == 1) ? Xk : Xv;
  const u16* Bt = Wt + (size_t)z * 1048576;
  __shared__ __attribute__((aligned(16))) u16 sA[2][128 * 32];
  __shared__ __attribute__((aligned(16))) u16 sB[2][128 * 32];
  const int t = threadIdx.x;
  const int w = t >> 6, lane = t & 63;
  const int lr = lane & 15, lg = lane >> 4;
  const int wr = w >> 1, wc = w & 1;
  const int row0 = by * 128, col0 = bx * 128;

  // A: reg-staged fp32. thread covers row t>>1, 16 cols at (t&1)*16
  const int arow = t >> 1, ahalf = t & 1;
  const float* gA = A + (size_t)(row0 + arow) * DD + ahalf * 16;
  const int aswz = arow & 3;
  // B: gload_lds, source unit pre-swizzled by dest row&3 (rule #21)
  const int srow = t >> 2;
  const int sunit = (t & 3) ^ (srow & 3);
  const u16* gB = Bt + (size_t)(col0 + srow) * DD + sunit * 8;
  const int ldsbase = w * 512;

  floatx4 acc[4][4] = {};
  float4 ar0, ar1, ar2, ar3;

  auto loadA = [&](int kt) {
    const float* p = gA + kt * 32;
    ar0 = *(const float4*)(p);
    ar1 = *(const float4*)(p + 4);
    ar2 = *(const float4*)(p + 8);
    ar3 = *(const float4*)(p + 12);
  };
  auto writeA = [&](int buf) {
    u32x4 w0, w1;
    w0.x = cvtpk_bf16(ar0.x, ar0.y); w0.y = cvtpk_bf16(ar0.z, ar0.w);
    w0.z = cvtpk_bf16(ar1.x, ar1.y); w0.w = cvtpk_bf16(ar1.z, ar1.w);
    w1.x = cvtpk_bf16(ar2.x, ar2.y); w1.y = cvtpk_bf16(ar2.z, ar2.w);
    w1.z = cvtpk_bf16(ar3.x, ar3.y); w1.w = cvtpk_bf16(ar3.z, ar3.w);
    *(u32x4*)&sA[buf][arow * 32 + ((ahalf * 2) ^ aswz) * 8] = w0;
    *(u32x4*)&sA[buf][arow * 32 + ((ahalf * 2 + 1) ^ aswz) * 8] = w1;
  };
  auto stageB = [&](int buf, int kt) {
    const int ko = kt * 32;
    gload16(gB + ko, &sB[buf][ldsbase]);
    gload16(gB + ko + (size_t)64 * DD, &sB[buf][2048 + ldsbase]);
  };

  // prologue
  loadA(0);
  stageB(0, 0);
  writeA(0);
  __syncthreads();

  const int fswz = lr & 3;  // frag-row&3 for rows m*16+lr
  int cur = 0;
  for (int kt = 0; kt < 32; ++kt) {
    if (kt + 1 < 32) {
      stageB(cur ^ 1, kt + 1);
      loadA(kt + 1);  // issue early; consumed by writeA after the MFMA phase
    }
    bhalf8 af[4], bf[4];
#pragma unroll
    for (int m = 0; m < 4; ++m)
      af[m] = *(const bhalf8*)&sA[cur][(wr * 64 + m * 16 + lr) * 32 + ((lg ^ fswz) * 8)];
#pragma unroll
    for (int n = 0; n < 4; ++n)
      bf[n] = *(const bhalf8*)&sB[cur][(wc * 64 + n * 16 + lr) * 32 + ((lg ^ fswz) * 8)];
#pragma unroll
    for (int m = 0; m < 4; ++m)
#pragma unroll
      for (int n = 0; n < 4; ++n)
        acc[m][n] = __builtin_amdgcn_mfma_f32_16x16x32_bf16(af[m], bf[n], acc[m][n], 0, 0, 0);
    if (kt + 1 < 32) writeA(cur ^ 1);
    __syncthreads();
    cur ^= 1;
  }

#pragma unroll
  for (int m = 0; m < 4; ++m) {
#pragma unroll
    for (int n = 0; n < 4; ++n) {
      const int col = col0 + wc * 64 + n * 16 + lr;
      const int rowb = row0 + wr * 64 + m * 16 + lg * 4;
      if (z == 2) {
        // V^T layout: Vtb[(b*1024 + col)][s]
        const int bidx = rowb >> 11, s = rowb & (SS - 1);
        ushort4 pk;
        pk.x = f2bf(acc[m][n][0]); pk.y = f2bf(acc[m][n][1]);
        pk.z = f2bf(acc[m][n][2]); pk.w = f2bf(acc[m][n][3]);
        *(ushort4*)&Vtb[((size_t)bidx * 1024 + col) * SS + s] = pk;
      } else {
        u16* C = (z == 0) ? Qb : Kb;
#pragma unroll
        for (int r = 0; r < 4; ++r)
          C[(size_t)(rowb + r) * DD + col] = f2bf(acc[m][n][r]);
      }
    }
  }
}

// ---------------- Wo GEMM: 1D grid 512, XCD-swizzled; 64x128 tile, fp32 out ----------
// A (merged bf16 Ob) and B staged via gload_lds with the same XOR swizzle.
__global__ __launch_bounds__(256, 2) void k_gemm_wo(
    const u16* __restrict__ A, const u16* __restrict__ Bt, float* __restrict__ C) {
  const int id = blockIdx.x;
  const int rr = id & 7, t8 = id >> 3;
  const int g = (t8 >> 3) * 8 + rr, c = t8 & 7;  // g rows, c cols
  const int by = g, bx = c;
  __shared__ __attribute__((aligned(16))) u16 sA[2][64 * 32];
  __shared__ __attribute__((aligned(16))) u16 sB[2][128 * 32];
  const int t = threadIdx.x;
  const int w = t >> 6, lane = t & 63;
  const int lr = lane & 15, lg = lane >> 4;
  const int wr = w >> 1, wc = w & 1;
  const int row0 = by * 64, col0 = bx * 128;

  const int srow = t >> 2;
  const int sunit = (t & 3) ^ (srow & 3);
  const u16* gA = A + (size_t)(row0 + srow) * DD + sunit * 8;
  const u16* gB = Bt + (size_t)(col0 + srow) * DD + sunit * 8;
  const int ldsbase = w * 512;

  floatx4 acc[2][4] = {};

  auto stage = [&](int buf, int kt) {
    const int ko = kt * 32;
    gload16(gA + ko, &sA[buf][ldsbase]);
    gload16(gB + ko, &sB[buf][ldsbase]);
    gload16(gB + ko + (size_t)64 * DD, &sB[buf][2048 + ldsbase]);
  };

  const int fswz = lr & 3;
  int cur = 0;
  stage(0, 0);
  __syncthreads();
  for (int kt = 0; kt < 32; ++kt) {
    if (kt + 1 < 32) stage(cur ^ 1, kt + 1);
    bhalf8 af[2], bf[4];
#pragma unroll
    for (int m = 0; m < 2; ++m)
      af[m] = *(const bhalf8*)&sA[cur][(wr * 32 + m * 16 + lr) * 32 + ((lg ^ fswz) * 8)];
#pragma unroll
    for (int n = 0; n < 4; ++n)
      bf[n] = *(const bhalf8*)&sB[cur][(wc * 64 + n * 16 + lr) * 32 + ((lg ^ fswz) * 8)];
#pragma unroll
    for (int m = 0; m < 2; ++m)
#pragma unroll
      for (int n = 0; n < 4; ++n)
        acc[m][n] = __builtin_amdgcn_mfma_f32_16x16x32_bf16(af[m], bf[n], acc[m][n], 0, 0, 0);
    __syncthreads();
    cur ^= 1;
  }

#pragma unroll
  for (int m = 0; m < 2; ++m)
#pragma unroll
    for (int n = 0; n < 4; ++n) {
      const int col = col0 + wc * 64 + n * 16 + lr;
      const int rowb = row0 + wr * 32 + m * 16 + lg * 4;
#pragma unroll
      for (int r = 0; r < 4; ++r)
        C[(size_t)(rowb + r) * DD + col] = acc[m][n][r];
    }
}

// ---------------- flash attention (LDS K/V, split-KV, XCD-swizzled grid) -------------
// 1D grid 1024*P, 256 threads = 4 waves, each wave owns 16 q-rows, KV tile = 64.
__global__ __launch_bounds__(256, 3) void k_attn(
    const u16* __restrict__ Q, const u16* __restrict__ K, const u16* __restrict__ Vt,
    float* __restrict__ Opart, float2* __restrict__ Ml,
    const int* __restrict__ valid_lens, const int part) {
  const int id = blockIdx.x;
  const int rr = id & 7, tt = id >> 3;
  const int g = (tt >> 5) * 8 + rr, c = tt & 31;  // g = zi*16 + h
  const int h = g & 15, zi = g >> 4;
  const int b = zi & 1, p = zi >> 1;
  const int t = threadIdx.x;
  const int w = t >> 6, lane = t & 63;
  const int lr = lane & 15, lg = lane >> 4;
  const int q0 = c * 64 + w * 16;
  const int vl = valid_lens[b];
  const int kbeg = p * part;
  if (kbeg >= vl) return;  // dead partition (uniform)
  const int kend = (vl < kbeg + part) ? vl : (kbeg + part);
  const int L = kend - kbeg;

  __shared__ __attribute__((aligned(16))) u16 kbuf[2][64 * 64];  // [key][dim] swizzled
  __shared__ __attribute__((aligned(16))) u16 vbuf[2][64 * 64];  // [d][key]  swizzled
  __shared__ __attribute__((aligned(16))) u16 p_lds[4][16 * 72]; // wave-private
  u16* pl = &p_lds[w][0];

  const u16* Qp = Q + ((size_t)(b * SS + q0 + lr)) * DD + h * DHD;
  const bhalf8 qf0 = *(const bhalf8*)(Qp + lg * 8);
  const bhalf8 qf1 = *(const bhalf8*)(Qp + 32 + lg * 8);

  // staging source (per-lane, pre-swizzled so linear LDS dest ends up swizzled)
  const int sub = lane >> 3;          // row-in-octet 0..7 (== row&7 of dest row)
  const int sc16 = (lane & 7) ^ sub;  // swizzled source col16
  const u16* ksrc = K + (size_t)(b * SS + kbeg + w * 16 + sub) * DD + h * DHD + sc16 * 8;
  const u16* vsrc = Vt + ((size_t)(b * HH + h) * DHD + w * 16 + sub) * SS + kbeg + sc16 * 8;

  auto stage = [&](int buf, int i) {
    const int sk0 = i * 64;
    gload16(ksrc + (size_t)sk0 * DD,       &kbuf[buf][(w * 16) * 64]);
    gload16(ksrc + (size_t)(sk0 + 8) * DD, &kbuf[buf][(w * 16 + 8) * 64]);
    gload16(vsrc + sk0,                    &vbuf[buf][(w * 16) * 64]);
    gload16(vsrc + (size_t)8 * SS + sk0,   &vbuf[buf][(w * 16 + 8) * 64]);
  };

  float mrun = -1e30f, lrun = 0.f;  // per-lane: stats of q-row (q0 + lr), log2 units
  floatx4 o[4] = {};                // o[dt]: C[q = lg*4+r][d = dt*16+lr]

  const int nblk = (L + 63) >> 6;
  const bool partial = (L & 63) != 0;
  const int swz = lr & 7;  // fragment-read swizzle (row&7 for rows c*16+lr / dt*16+lr)

  stage(0, 0);
  __syncthreads();

  int cb = 0;
  for (int i = 0; i < nblk; ++i) {
    if (i + 1 < nblk) stage(cb ^ 1, i + 1);
    const u16* kb = &kbuf[cb][0];
    const u16* vb = &vbuf[cb][0];
    // QK^T from LDS K-frags
    floatx4 s[4];
    __builtin_amdgcn_s_setprio(1);
#pragma unroll
    for (int cc = 0; cc < 4; ++cc) {
      const bhalf8 kc0 = *(const bhalf8*)&kb[(cc * 16 + lr) * 64 + ((lg ^ swz) * 8)];
      const bhalf8 kc1 = *(const bhalf8*)&kb[(cc * 16 + lr) * 64 + (((lg + 4) ^ swz) * 8)];
      floatx4 zz = {0.f, 0.f, 0.f, 0.f};
      zz = __builtin_amdgcn_mfma_f32_16x16x32_bf16(kc0, qf0, zz, 0, 0, 0);
      s[cc] = __builtin_amdgcn_mfma_f32_16x16x32_bf16(kc1, qf1, zz, 0, 0, 0);
    }
    __builtin_amdgcn_s_setprio(0);
    // mask tail keys (uniform branch; key index is per-reg)
    if (partial && i == nblk - 1) {
      const int sk0 = i * 64;
#pragma unroll
      for (int cc = 0; cc < 4; ++cc)
#pragma unroll
        for (int r = 0; r < 4; ++r)
          if (sk0 + cc * 16 + lg * 4 + r >= L) s[cc][r] = -1e6f;
    }
    // row max: in-register tree + 2 cross-lane steps
    float tmax = fmaxf(fmaxf(fmaxf(s[0][0], s[0][1]), fmaxf(s[0][2], s[0][3])),
                       fmaxf(fmaxf(s[1][0], s[1][1]), fmaxf(s[1][2], s[1][3])));
    tmax = fmaxf(tmax, fmaxf(fmaxf(fmaxf(s[2][0], s[2][1]), fmaxf(s[2][2], s[2][3])),
                             fmaxf(fmaxf(s[3][0], s[3][1]), fmaxf(s[3][2], s[3][3]))));
    tmax = fmaxf(tmax, __shfl_xor(tmax, 16));
    tmax = fmaxf(tmax, __shfl_xor(tmax, 32));
    // defer-max: skip O-rescale while max growth <= 8 (log2 units; P bounded by 256)
    if (!__all(tmax <= mrun + 8.0f)) {
      const float nm = fmaxf(mrun, tmax);
      const float sc = exp2_fast(mrun - nm);
      mrun = nm;
      lrun *= sc;
      float scb[4];
#pragma unroll
      for (int r = 0; r < 4; ++r) scb[r] = __shfl(sc, lg * 4 + r);
#pragma unroll
      for (int dt = 0; dt < 4; ++dt)
#pragma unroll
        for (int r = 0; r < 4; ++r) o[dt][r] *= scb[r];
    }
    // p = exp2(s - m), row sum, pack to bf16 pairs
    float rs = 0.f;
    u32 pk[4][2];
#pragma unroll
    for (int cc = 0; cc < 4; ++cc) {
      float p0 = exp2_fast(s[cc][0] - mrun), p1 = exp2_fast(s[cc][1] - mrun);
      float p2 = exp2_fast(s[cc][2] - mrun), p3 = exp2_fast(s[cc][3] - mrun);
      rs += (p0 + p1) + (p2 + p3);
      pk[cc][0] = cvtpk_bf16(p0, p1);
      pk[cc][1] = cvtpk_bf16(p2, p3);
    }
    rs += __shfl_xor(rs, 16);
    rs += __shfl_xor(rs, 32);
    lrun += rs;
    // P -> wave-private LDS: lane writes its own q-row (lr)
#pragma unroll
    for (int cc = 0; cc < 4; ++cc) {
      u32x2 pr; pr.x = pk[cc][0]; pr.y = pk[cc][1];
      *(u32x2*)&pl[lr * 72 + cc * 16 + lg * 4] = pr;
    }
    asm volatile("s_waitcnt lgkmcnt(0)" ::: "memory");  // in-wave write->read ordering
    const bhalf8 pa0 = *(const bhalf8*)&pl[lr * 72 + lg * 8];
    const bhalf8 pa1 = *(const bhalf8*)&pl[lr * 72 + 32 + lg * 8];
    // PV from LDS V-frags
    __builtin_amdgcn_s_setprio(1);
#pragma unroll
    for (int dt = 0; dt < 4; ++dt) {
      const bhalf8 vf0 = *(const bhalf8*)&vb[(dt * 16 + lr) * 64 + ((lg ^ swz) * 8)];
      const bhalf8 vf1 = *(const bhalf8*)&vb[(dt * 16 + lr) * 64 + (((lg + 4) ^ swz) * 8)];
      o[dt] = __builtin_amdgcn_mfma_f32_16x16x32_bf16(pa0, vf0, o[dt], 0, 0, 0);
      o[dt] = __builtin_amdgcn_mfma_f32_16x16x32_bf16(pa1, vf1, o[dt], 0, 0, 0);
    }
    __builtin_amdgcn_s_setprio(0);
    __syncthreads();  // staging of next tile drained + all waves done with cb
    cb ^= 1;
  }

  // epilogue: store unnormalized partial + (m, l)
  const size_t rowbase = ((size_t)(b * HH + h)) * SS + q0;
  const size_t pbase = (size_t)p * (BB * HH * SS);
#pragma unroll
  for (int dt = 0; dt < 4; ++dt)
#pragma unroll
    for (int r = 0; r < 4; ++r)
      Opart[(pbase + rowbase + lg * 4 + r) * DHD + dt * 16 + lr] = o[dt][r];
  if (lane < 16) {
    float2 ml; ml.x = mrun; ml.y = lrun;
    Ml[pbase + rowbase + lr] = ml;
  }
}

// ---------------- merge split-KV partials -> bf16 merged-head output -----------------
template <int P>
__global__ void k_merge(const float* __restrict__ Opart, const float2* __restrict__ Ml,
                        const int* __restrict__ valid_lens, u16* __restrict__ Ob) {
  const int t = threadIdx.x;
  const int rid = blockIdx.x * 16 + (t >> 4);  // [0, B*H*S)
  const int dc = t & 15;
  const int b = rid >> 15;
  const int h = (rid >> 11) & (HH - 1);
  const int s = rid & (SS - 1);
  const int vl = valid_lens[b];
  constexpr int part = SS / P;
  float m[P], l[P];
  float4 o4[P];
  bool live[P];
  float M = -1e30f;
#pragma unroll
  for (int p = 0; p < P; ++p) {
    live[p] = (p * part < vl);
    if (live[p]) {
      float2 ml = Ml[(size_t)p * (BB * HH * SS) + rid];
      m[p] = ml.x; l[p] = ml.y;
      o4[p] = *(const float4*)&Opart[((size_t)p * (BB * HH * SS) + rid) * DHD + dc * 4];
      M = fmaxf(M, m[p]);
    }
  }
  float L = 0.f;
  float4 acc = {0.f, 0.f, 0.f, 0.f};
#pragma unroll
  for (int p = 0; p < P; ++p)
    if (live[p]) {
      const float wgt = exp2_fast(m[p] - M);
      L += l[p] * wgt;
      acc.x += wgt * o4[p].x; acc.y += wgt * o4[p].y;
      acc.z += wgt * o4[p].z; acc.w += wgt * o4[p].w;
    }
  const float inv = 1.0f / L;
  ushort4 r;
  r.x = f2bf(acc.x * inv); r.y = f2bf(acc.y * inv);
  r.z = f2bf(acc.z * inv); r.w = f2bf(acc.w * inv);
  *(ushort4*)&Ob[((size_t)(b * SS + s)) * DD + h * DHD + dc * 4] = r;
}

extern "C" void kernel_launch(void* const* d_in, const int* in_sizes, int n_in,
                              void* d_out, int out_size, void* d_ws, size_t ws_size,
                              hipStream_t stream) {
  const float* q = (const float*)d_in[0];
  const float* k = (const float*)d_in[1];
  const float* v = (const float*)d_in[2];
  const int* vl = (const int*)d_in[3];
  const float* Wq = (const float*)d_in[4];
  const float* Wk = (const float*)d_in[5];
  const float* Wv = (const float*)d_in[6];
  const float* Wo = (const float*)d_in[7];

  char* ws = (char*)d_ws;
  u16* Wt  = (u16*)(ws + 0);          // 4 x 2 MiB transposed weights
  u16* Qb  = (u16*)(ws + 8388608);    // 8 MiB each
  u16* Kb  = (u16*)(ws + 16777216);
  u16* Vtb = (u16*)(ws + 25165824);
  u16* Ob  = (u16*)(ws + 33554432);   // 8 MiB merged-head attention output

  // split-KV partials: P=2 when workspace allows; else P=1
  const bool big = ws_size >= (size_t)134 * 1024 * 1024;
  const int P = big ? 2 : 1;
  const int part = SS / P;
  float* Opart = (float*)(ws + 50331648);                       // P x 16 MiB fp32
  float2* Ml   = big ? (float2*)(ws + 92274688) : (float2*)(ws + 67108864);

  k_transpose4<<<dim3(32, 32, 4), dim3(32, 8), 0, stream>>>(Wq, Wk, Wv, Wo, Wt);
  k_gemm_qkv<<<768, 256, 0, stream>>>(q, k, v, Wt, Qb, Kb, Vtb);
  k_attn<<<1024 * P, 256, 0, stream>>>(Qb, Kb, Vtb, Opart, Ml, vl, part);
  if (big) k_merge<2><<<4096, 256, 0, stream>>>(Opart, Ml, vl, Ob);
  else     k_merge<1><<<4096, 256, 0, stream>>>(Opart, Ml, vl, Ob);
  u16* Wto = Wt + 3 * 1048576;
  k_gemm_wo<<<512, 256, 0, stream>>>(Ob, Wto, (float*)d_out);
}

// Round 10
// 208.417 us; speedup vs baseline: 1.0968x; 1.0531x over previous
//
#include <hip/hip_runtime.h>
#include <stdint.h>

// Problem constants
#define BB 2
#define SS 2048
#define DD 1024
#define HH 16
#define DHD 64
#define MM (BB * SS)  // 4096

typedef unsigned short u16;
typedef unsigned int u32;
typedef __attribute__((ext_vector_type(8))) short bhalf8;   // 8 bf16 in 4 VGPRs
typedef __attribute__((ext_vector_type(4))) float floatx4;  // MFMA 16x16 accumulator
typedef __attribute__((ext_vector_type(2))) u32 u32x2;
typedef __attribute__((address_space(3))) u32 as3_u32;
typedef __attribute__((address_space(1))) u32 as1_u32;

__device__ __forceinline__ u16 f2bf(float f) {
  u32 u = __float_as_uint(f);
  u32 r = (u + 0x7FFFu + ((u >> 16) & 1u)) >> 16;  // RNE
  return (u16)r;
}

__device__ __forceinline__ u32 cvtpk_bf16(float lo, float hi) {
  u32 r;
  asm("v_cvt_pk_bf16_f32 %0, %1, %2" : "=v"(r) : "v"(lo), "v"(hi));
  return r;
}

__device__ __forceinline__ float exp2_fast(float x) {  // v_exp_f32 computes 2^x
  float r;
  asm("v_exp_f32 %0, %1" : "=v"(r) : "v"(x));
  return r;
}

// async global->LDS, 16B per lane; lds dest must be wave-uniform base (+lane*16 by HW)
__device__ __forceinline__ void gload16(const void* g, const void* l) {
  __builtin_amdgcn_global_load_lds((as1_u32*)(uintptr_t)g, (as3_u32*)(uintptr_t)l, 16, 0, 0);
}

// ---------------- fused prep: fp32->bf16 convert (roles 0..2) + W transposes (role 3)
// grid (4096, 4) x 256 threads. role<3: vectorized convert of q/k/v into X.
// role==3: all four 32x32-tiled weight transposes (z = blockIdx.x>>10).
// z==0 (Wq) folds 0.125 * log2(e) so attention scores come out in log2 units.
__global__ void k_prep(const float* __restrict__ q, const float* __restrict__ k,
                       const float* __restrict__ v, const float* __restrict__ Wq,
                       const float* __restrict__ Wk, const float* __restrict__ Wv,
                       const float* __restrict__ Wo, u16* __restrict__ X,
                       u16* __restrict__ Wt) {
  const int role = blockIdx.y;
  const int t = threadIdx.x;
  if (role < 3) {
    const float* src = (role == 0) ? q : (role == 1) ? k : v;
    const int i = blockIdx.x * 256 + t;  // 4096*256 == (4M)/4 exactly
    float4 val = ((const float4*)src)[i];
    ushort4 o;
    o.x = f2bf(val.x); o.y = f2bf(val.y); o.z = f2bf(val.z); o.w = f2bf(val.w);
    ((ushort4*)(X + (size_t)role * 4194304))[i] = o;
  } else {
    const int z = blockIdx.x >> 10;       // 0..3
    const int tile = blockIdx.x & 1023;
    const int bx = tile & 31, by = tile >> 5;
    const float* W = (z == 0) ? Wq : (z == 1) ? Wk : (z == 2) ? Wv : Wo;
    const float sc = (z == 0) ? 0.18033688011112042f : 1.0f;  // 0.125 * log2(e)
    __shared__ u16 stile[32][33];
    const int tx = t & 31, ty = t >> 5;   // (32, 8)
    const int n0 = bx * 32, k0 = by * 32;
#pragma unroll
    for (int i = 0; i < 4; ++i)
      stile[ty + 8 * i][tx] = f2bf(W[(size_t)(k0 + ty + 8 * i) * DD + n0 + tx] * sc);
    __syncthreads();
    u16* dst = Wt + (size_t)z * 1048576;
#pragma unroll
    for (int i = 0; i < 4; ++i)
      dst[(size_t)(n0 + ty + 8 * i) * DD + k0 + tx] = stile[tx][ty + 8 * i];
  }
}

// ---------------- fused QKV GEMM: 1D grid 768, XCD-swizzled; 128x128 tile, BK=32 -----
// id = r + 8*(a*8 + c): the 8 col-blocks (c) of group g=8a+r share id%8 -> same XCD,
// so each A row-panel is fetched into one XCD's L2 instead of all eight.
__global__ __launch_bounds__(256, 2) void k_gemm_qkv(
    const u16* __restrict__ Xq, const u16* __restrict__ Xk, const u16* __restrict__ Xv,
    const u16* __restrict__ Wt, u16* __restrict__ Qb, u16* __restrict__ Kb,
    u16* __restrict__ Vtb) {
  const int id = blockIdx.x;
  const int rr = id & 7, t8 = id >> 3;
  const int g = (t8 >> 3) * 8 + rr, c = t8 & 7;  // g in [0,96), c in [0,8)
  const int z = g / 32, by = g % 32, bx = c;
  const u16* A = (z == 0) ? Xq : (z == 1) ? Xk : Xv;
  const u16* Bt = Wt + (size_t)z * 1048576;
  __shared__ __attribute__((aligned(16))) u16 sA[2][128 * 32];
  __shared__ __attribute__((aligned(16))) u16 sB[2][128 * 32];
  const int t = threadIdx.x;
  const int w = t >> 6, lane = t & 63;
  const int lr = lane & 15, lg = lane >> 4;
  const int wr = w >> 1, wc = w & 1;
  const int row0 = by * 128, col0 = bx * 128;

  const int srow = t >> 2;
  const int skoff = (t & 3) * 8;
  const u16* gA = A + (size_t)(row0 + srow) * DD + skoff;
  const u16* gB = Bt + (size_t)(col0 + srow) * DD + skoff;
  const int ldsbase = w * 512;

  floatx4 acc[4][4] = {};

  auto stage = [&](int buf, int kt) {
    const int ko = kt * 32;
    gload16(gA + ko, &sA[buf][ldsbase]);
    gload16(gA + ko + (size_t)64 * DD, &sA[buf][2048 + ldsbase]);
    gload16(gB + ko, &sB[buf][ldsbase]);
    gload16(gB + ko + (size_t)64 * DD, &sB[buf][2048 + ldsbase]);
  };

  int cur = 0;
  stage(0, 0);
  __syncthreads();
  for (int kt = 0; kt < 32; ++kt) {
    if (kt + 1 < 32) stage(cur ^ 1, kt + 1);
    bhalf8 af[4], bf[4];
#pragma unroll
    for (int m = 0; m < 4; ++m)
      af[m] = *(const bhalf8*)&sA[cur][(wr * 64 + m * 16 + lr) * 32 + lg * 8];
#pragma unroll
    for (int n = 0; n < 4; ++n)
      bf[n] = *(const bhalf8*)&sB[cur][(wc * 64 + n * 16 + lr) * 32 + lg * 8];
#pragma unroll
    for (int m = 0; m < 4; ++m)
#pragma unroll
      for (int n = 0; n < 4; ++n)
        acc[m][n] = __builtin_amdgcn_mfma_f32_16x16x32_bf16(af[m], bf[n], acc[m][n], 0, 0, 0);
    __syncthreads();
    cur ^= 1;
  }

#pragma unroll
  for (int m = 0; m < 4; ++m) {
#pragma unroll
    for (int n = 0; n < 4; ++n) {
      const int col = col0 + wc * 64 + n * 16 + lr;
      const int rowb = row0 + wr * 64 + m * 16 + lg * 4;
      if (z == 2) {
        // V^T layout: Vtb[(b*1024 + col)][s]
        const int bidx = rowb >> 11, s = rowb & (SS - 1);
        ushort4 pk;
        pk.x = f2bf(acc[m][n][0]); pk.y = f2bf(acc[m][n][1]);
        pk.z = f2bf(acc[m][n][2]); pk.w = f2bf(acc[m][n][3]);
        *(ushort4*)&Vtb[((size_t)bidx * 1024 + col) * SS + s] = pk;
      } else {
        u16* C = (z == 0) ? Qb : Kb;
#pragma unroll
        for (int r = 0; r < 4; ++r)
          C[(size_t)(rowb + r) * DD + col] = f2bf(acc[m][n][r]);
      }
    }
  }
}

// ---------------- Wo GEMM: 1D grid 512, XCD-swizzled; 64x128 tile, fp32 out ----------
__global__ __launch_bounds__(256, 2) void k_gemm_wo(
    const u16* __restrict__ A, const u16* __restrict__ Bt, float* __restrict__ C) {
  const int id = blockIdx.x;
  const int rr = id & 7, t8 = id >> 3;
  const int g = (t8 >> 3) * 8 + rr, c = t8 & 7;  // g in [0,64) rows, c in [0,8) cols
  const int by = g, bx = c;
  __shared__ __attribute__((aligned(16))) u16 sA[2][64 * 32];
  __shared__ __attribute__((aligned(16))) u16 sB[2][128 * 32];
  const int t = threadIdx.x;
  const int w = t >> 6, lane = t & 63;
  const int lr = lane & 15, lg = lane >> 4;
  const int wr = w >> 1, wc = w & 1;
  const int row0 = by * 64, col0 = bx * 128;

  const int srow = t >> 2;
  const int skoff = (t & 3) * 8;
  const u16* gA = A + (size_t)(row0 + srow) * DD + skoff;
  const u16* gB = Bt + (size_t)(col0 + srow) * DD + skoff;
  const int ldsbase = w * 512;

  floatx4 acc[2][4] = {};

  auto stage = [&](int buf, int kt) {
    const int ko = kt * 32;
    gload16(gA + ko, &sA[buf][ldsbase]);
    gload16(gB + ko, &sB[buf][ldsbase]);
    gload16(gB + ko + (size_t)64 * DD, &sB[buf][2048 + ldsbase]);
  };

  int cur = 0;
  stage(0, 0);
  __syncthreads();
  for (int kt = 0; kt < 32; ++kt) {
    if (kt + 1 < 32) stage(cur ^ 1, kt + 1);
    bhalf8 af[2], bf[4];
#pragma unroll
    for (int m = 0; m < 2; ++m)
      af[m] = *(const bhalf8*)&sA[cur][(wr * 32 + m * 16 + lr) * 32 + lg * 8];
#pragma unroll
    for (int n = 0; n < 4; ++n)
      bf[n] = *(const bhalf8*)&sB[cur][(wc * 64 + n * 16 + lr) * 32 + lg * 8];
#pragma unroll
    for (int m = 0; m < 2; ++m)
#pragma unroll
      for (int n = 0; n < 4; ++n)
        acc[m][n] = __builtin_amdgcn_mfma_f32_16x16x32_bf16(af[m], bf[n], acc[m][n], 0, 0, 0);
    __syncthreads();
    cur ^= 1;
  }

#pragma unroll
  for (int m = 0; m < 2; ++m)
#pragma unroll
    for (int n = 0; n < 4; ++n) {
      const int col = col0 + wc * 64 + n * 16 + lr;
      const int rowb = row0 + wr * 32 + m * 16 + lg * 4;
#pragma unroll
      for (int r = 0; r < 4; ++r)
        C[(size_t)(rowb + r) * DD + col] = acc[m][n][r];
    }
}

// ---------------- flash attention (LDS K/V, split-KV, XCD-swizzled grid) -------------
// 1D grid 1024*P, 256 threads = 4 waves, each wave owns 16 q-rows, KV tile = 64.
// id = r + 8*(a*32 + c): 32 q-blocks (c) of group g=8a+r (= one (h,b,p)) share id%8
// -> same XCD -> the K/V slice is fetched into one L2, reused by all 32 q-blocks.
__global__ __launch_bounds__(256, 2) void k_attn(
    const u16* __restrict__ Q, const u16* __restrict__ K, const u16* __restrict__ Vt,
    float* __restrict__ Opart, float2* __restrict__ Ml,
    const int* __restrict__ valid_lens, const int part) {
  const int id = blockIdx.x;
  const int rr = id & 7, tt = id >> 3;
  const int g = (tt >> 5) * 8 + rr, c = tt & 31;  // g = zi*16 + h
  const int h = g & 15, zi = g >> 4;
  const int b = zi & 1, p = zi >> 1;
  const int t = threadIdx.x;
  const int w = t >> 6, lane = t & 63;
  const int lr = lane & 15, lg = lane >> 4;
  const int q0 = c * 64 + w * 16;
  const int vl = valid_lens[b];
  const int kbeg = p * part;
  if (kbeg >= vl) return;  // dead partition (uniform)
  const int kend = (vl < kbeg + part) ? vl : (kbeg + part);
  const int L = kend - kbeg;

  __shared__ __attribute__((aligned(16))) u16 kbuf[2][64 * 64];  // [key][dim] swizzled
  __shared__ __attribute__((aligned(16))) u16 vbuf[2][64 * 64];  // [d][key]  swizzled
  __shared__ __attribute__((aligned(16))) u16 p_lds[4][16 * 72]; // wave-private
  u16* pl = &p_lds[w][0];

  const u16* Qp = Q + ((size_t)(b * SS + q0 + lr)) * DD + h * DHD;
  const bhalf8 qf0 = *(const bhalf8*)(Qp + lg * 8);
  const bhalf8 qf1 = *(const bhalf8*)(Qp + 32 + lg * 8);

  // staging source (per-lane, pre-swizzled so linear LDS dest ends up swizzled)
  const int sub = lane >> 3;          // row-in-octet 0..7 (== row&7 of dest row)
  const int sc16 = (lane & 7) ^ sub;  // swizzled source col16
  const u16* ksrc = K + (size_t)(b * SS + kbeg + w * 16 + sub) * DD + h * DHD + sc16 * 8;
  const u16* vsrc = Vt + ((size_t)(b * HH + h) * DHD + w * 16 + sub) * SS + kbeg + sc16 * 8;

  auto stage = [&](int buf, int i) {
    const int sk0 = i * 64;
    gload16(ksrc + (size_t)sk0 * DD,       &kbuf[buf][(w * 16) * 64]);
    gload16(ksrc + (size_t)(sk0 + 8) * DD, &kbuf[buf][(w * 16 + 8) * 64]);
    gload16(vsrc + sk0,                    &vbuf[buf][(w * 16) * 64]);
    gload16(vsrc + (size_t)8 * SS + sk0,   &vbuf[buf][(w * 16 + 8) * 64]);
  };

  float mrun = -1e30f, lrun = 0.f;  // per-lane: stats of q-row (q0 + lr), log2 units
  floatx4 o[4] = {};                // o[dt]: C[q = lg*4+r][d = dt*16+lr]

  const int nblk = (L + 63) >> 6;
  const bool partial = (L & 63) != 0;
  const int swz = lr & 7;  // fragment-read swizzle (row&7 for rows c*16+lr / dt*16+lr)

  stage(0, 0);
  __syncthreads();

  int cb = 0;
  for (int i = 0; i < nblk; ++i) {
    if (i + 1 < nblk) stage(cb ^ 1, i + 1);
    const u16* kb = &kbuf[cb][0];
    const u16* vb = &vbuf[cb][0];
    // QK^T from LDS K-frags
    floatx4 s[4];
    __builtin_amdgcn_s_setprio(1);
#pragma unroll
    for (int cc = 0; cc < 4; ++cc) {
      const bhalf8 kc0 = *(const bhalf8*)&kb[(cc * 16 + lr) * 64 + ((lg ^ swz) * 8)];
      const bhalf8 kc1 = *(const bhalf8*)&kb[(cc * 16 + lr) * 64 + (((lg + 4) ^ swz) * 8)];
      floatx4 zz = {0.f, 0.f, 0.f, 0.f};
      zz = __builtin_amdgcn_mfma_f32_16x16x32_bf16(kc0, qf0, zz, 0, 0, 0);
      s[cc] = __builtin_amdgcn_mfma_f32_16x16x32_bf16(kc1, qf1, zz, 0, 0, 0);
    }
    __builtin_amdgcn_s_setprio(0);
    // mask tail keys (uniform branch; key index is per-reg)
    if (partial && i == nblk - 1) {
      const int sk0 = i * 64;
#pragma unroll
      for (int cc = 0; cc < 4; ++cc)
#pragma unroll
        for (int r = 0; r < 4; ++r)
          if (sk0 + cc * 16 + lg * 4 + r >= L) s[cc][r] = -1e6f;
    }
    // row max: in-register tree + 2 cross-lane steps
    float tmax = fmaxf(fmaxf(fmaxf(s[0][0], s[0][1]), fmaxf(s[0][2], s[0][3])),
                       fmaxf(fmaxf(s[1][0], s[1][1]), fmaxf(s[1][2], s[1][3])));
    tmax = fmaxf(tmax, fmaxf(fmaxf(fmaxf(s[2][0], s[2][1]), fmaxf(s[2][2], s[2][3])),
                             fmaxf(fmaxf(s[3][0], s[3][1]), fmaxf(s[3][2], s[3][3]))));
    tmax = fmaxf(tmax, __shfl_xor(tmax, 16));
    tmax = fmaxf(tmax, __shfl_xor(tmax, 32));
    // defer-max: skip O-rescale while max growth <= 8 (log2 units; P bounded by 256)
    if (!__all(tmax <= mrun + 8.0f)) {
      const float nm = fmaxf(mrun, tmax);
      const float sc = exp2_fast(mrun - nm);
      mrun = nm;
      lrun *= sc;
      float scb[4];
#pragma unroll
      for (int r = 0; r < 4; ++r) scb[r] = __shfl(sc, lg * 4 + r);
#pragma unroll
      for (int dt = 0; dt < 4; ++dt)
#pragma unroll
        for (int r = 0; r < 4; ++r) o[dt][r] *= scb[r];
    }
    // p = exp2(s - m), row sum, pack to bf16 pairs
    float rs = 0.f;
    u32 pk[4][2];
#pragma unroll
    for (int cc = 0; cc < 4; ++cc) {
      float p0 = exp2_fast(s[cc][0] - mrun), p1 = exp2_fast(s[cc][1] - mrun);
      float p2 = exp2_fast(s[cc][2] - mrun), p3 = exp2_fast(s[cc][3] - mrun);
      rs += (p0 + p1) + (p2 + p3);
      pk[cc][0] = cvtpk_bf16(p0, p1);
      pk[cc][1] = cvtpk_bf16(p2, p3);
    }
    rs += __shfl_xor(rs, 16);
    rs += __shfl_xor(rs, 32);
    lrun += rs;
    // P -> wave-private LDS: lane writes its own q-row (lr)
#pragma unroll
    for (int cc = 0; cc < 4; ++cc) {
      u32x2 pr; pr.x = pk[cc][0]; pr.y = pk[cc][1];
      *(u32x2*)&pl[lr * 72 + cc * 16 + lg * 4] = pr;
    }
    asm volatile("s_waitcnt lgkmcnt(0)" ::: "memory");  // in-wave write->read ordering
    const bhalf8 pa0 = *(const bhalf8*)&pl[lr * 72 + lg * 8];
    const bhalf8 pa1 = *(const bhalf8*)&pl[lr * 72 + 32 + lg * 8];
    // PV from LDS V-frags
    __builtin_amdgcn_s_setprio(1);
#pragma unroll
    for (int dt = 0; dt < 4; ++dt) {
      const bhalf8 vf0 = *(const bhalf8*)&vb[(dt * 16 + lr) * 64 + ((lg ^ swz) * 8)];
      const bhalf8 vf1 = *(const bhalf8*)&vb[(dt * 16 + lr) * 64 + (((lg + 4) ^ swz) * 8)];
      o[dt] = __builtin_amdgcn_mfma_f32_16x16x32_bf16(pa0, vf0, o[dt], 0, 0, 0);
      o[dt] = __builtin_amdgcn_mfma_f32_16x16x32_bf16(pa1, vf1, o[dt], 0, 0, 0);
    }
    __builtin_amdgcn_s_setprio(0);
    __syncthreads();  // staging of next tile drained + all waves done with cb
    cb ^= 1;
  }

  // epilogue: store unnormalized partial + (m, l)
  const size_t rowbase = ((size_t)(b * HH + h)) * SS + q0;
  const size_t pbase = (size_t)p * (BB * HH * SS);
#pragma unroll
  for (int dt = 0; dt < 4; ++dt)
#pragma unroll
    for (int r = 0; r < 4; ++r)
      Opart[(pbase + rowbase + lg * 4 + r) * DHD + dt * 16 + lr] = o[dt][r];
  if (lane < 16) {
    float2 ml; ml.x = mrun; ml.y = lrun;
    Ml[pbase + rowbase + lr] = ml;
  }
}

// ---------------- merge split-KV partials -> bf16 merged-head output -----------------
template <int P>
__global__ void k_merge(const float* __restrict__ Opart, const float2* __restrict__ Ml,
                        const int* __restrict__ valid_lens, u16* __restrict__ Ob) {
  const int t = threadIdx.x;
  const int rid = blockIdx.x * 16 + (t >> 4);  // [0, B*H*S)
  const int dc = t & 15;
  const int b = rid >> 15;
  const int h = (rid >> 11) & (HH - 1);
  const int s = rid & (SS - 1);
  const int vl = valid_lens[b];
  constexpr int part = SS / P;
  float m[P], l[P];
  float4 o4[P];
  bool live[P];
  float M = -1e30f;
#pragma unroll
  for (int p = 0; p < P; ++p) {
    live[p] = (p * part < vl);
    if (live[p]) {
      float2 ml = Ml[(size_t)p * (BB * HH * SS) + rid];
      m[p] = ml.x; l[p] = ml.y;
      o4[p] = *(const float4*)&Opart[((size_t)p * (BB * HH * SS) + rid) * DHD + dc * 4];
      M = fmaxf(M, m[p]);
    }
  }
  float L = 0.f;
  float4 acc = {0.f, 0.f, 0.f, 0.f};
#pragma unroll
  for (int p = 0; p < P; ++p)
    if (live[p]) {
      const float wgt = exp2_fast(m[p] - M);
      L += l[p] * wgt;
      acc.x += wgt * o4[p].x; acc.y += wgt * o4[p].y;
      acc.z += wgt * o4[p].z; acc.w += wgt * o4[p].w;
    }
  const float inv = 1.0f / L;
  ushort4 r;
  r.x = f2bf(acc.x * inv); r.y = f2bf(acc.y * inv);
  r.z = f2bf(acc.z * inv); r.w = f2bf(acc.w * inv);
  *(ushort4*)&Ob[((size_t)(b * SS + s)) * DD + h * DHD + dc * 4] = r;
}

extern "C" void kernel_launch(void* const* d_in, const int* in_sizes, int n_in,
                              void* d_out, int out_size, void* d_ws, size_t ws_size,
                              hipStream_t stream) {
  const float* q = (const float*)d_in[0];
  const float* k = (const float*)d_in[1];
  const float* v = (const float*)d_in[2];
  const int* vl = (const int*)d_in[3];
  const float* Wq = (const float*)d_in[4];
  const float* Wk = (const float*)d_in[5];
  const float* Wv = (const float*)d_in[6];
  const float* Wo = (const float*)d_in[7];

  char* ws = (char*)d_ws;
  u16* Xq  = (u16*)(ws + 0);          // 3 x 8 MiB bf16 inputs (dead after qkv GEMM)
  u16* Wt  = (u16*)(ws + 25165824);   // 4 x 2 MiB transposed weights
  u16* Qb  = (u16*)(ws + 33554432);   // 8 MiB each
  u16* Kb  = (u16*)(ws + 41943040);
  u16* Vtb = (u16*)(ws + 50331648);
  u16* Ob  = (u16*)(ws + 58720256);   // 8 MiB merged-head attention output

  // split-KV partials: P=2 when workspace allows; else P=1 overlaying dead Xq
  const bool big = ws_size >= (size_t)134 * 1024 * 1024;
  const int P = big ? 2 : 1;
  const int part = SS / P;
  float* Opart = big ? (float*)(ws + 67108864) : (float*)(ws + 0);
  float2* Ml   = big ? (float2*)(ws + 100663296) : (float2*)(ws + 16777216);

  k_prep<<<dim3(4096, 4), 256, 0, stream>>>(q, k, v, Wq, Wk, Wv, Wo, Xq, Wt);
  k_gemm_qkv<<<768, 256, 0, stream>>>(Xq, Xq + 4194304, Xq + 8388608, Wt, Qb, Kb, Vtb);
  k_attn<<<1024 * P, 256, 0, stream>>>(Qb, Kb, Vtb, Opart, Ml, vl, part);
  if (big) k_merge<2><<<4096, 256, 0, stream>>>(Opart, Ml, vl, Ob);
  else     k_merge<1><<<4096, 256, 0, stream>>>(Opart, Ml, vl, Ob);
  u16* Wto = Wt + 3 * 1048576;
  k_gemm_wo<<<512, 256, 0, stream>>>(Ob, Wto, (float*)d_out);
}

// Round 11
// 195.454 us; speedup vs baseline: 1.1695x; 1.0663x over previous
//
#include <hip/hip_runtime.h>
#include <stdint.h>

// Problem constants
#define BB 2
#define SS 2048
#define DD 1024
#define HH 16
#define DHD 64
#define MM (BB * SS)  // 4096

typedef unsigned short u16;
typedef unsigned int u32;
typedef __attribute__((ext_vector_type(8))) short bhalf8;   // 8 bf16 in 4 VGPRs
typedef __attribute__((ext_vector_type(4))) float floatx4;  // MFMA 16x16 accumulator
typedef __attribute__((ext_vector_type(2))) u32 u32x2;
typedef __attribute__((address_space(3))) u32 as3_u32;
typedef __attribute__((address_space(1))) u32 as1_u32;

__device__ __forceinline__ u16 f2bf(float f) {
  u32 u = __float_as_uint(f);
  u32 r = (u + 0x7FFFu + ((u >> 16) & 1u)) >> 16;  // RNE
  return (u16)r;
}

__device__ __forceinline__ u32 cvtpk_bf16(float lo, float hi) {
  u32 r;
  asm("v_cvt_pk_bf16_f32 %0, %1, %2" : "=v"(r) : "v"(lo), "v"(hi));
  return r;
}

__device__ __forceinline__ float exp2_fast(float x) {  // v_exp_f32 computes 2^x
  float r;
  asm("v_exp_f32 %0, %1" : "=v"(r) : "v"(x));
  return r;
}

// async global->LDS, 16B per lane; lds dest must be wave-uniform base (+lane*16 by HW)
__device__ __forceinline__ void gload16(const void* g, const void* l) {
  __builtin_amdgcn_global_load_lds((as1_u32*)(uintptr_t)g, (as3_u32*)(uintptr_t)l, 16, 0, 0);
}

// ---------------- fused prep: fp32->bf16 convert (roles 0..2) + W transposes (role 3)
__global__ void k_prep(const float* __restrict__ q, const float* __restrict__ k,
                       const float* __restrict__ v, const float* __restrict__ Wq,
                       const float* __restrict__ Wk, const float* __restrict__ Wv,
                       const float* __restrict__ Wo, u16* __restrict__ X,
                       u16* __restrict__ Wt) {
  const int role = blockIdx.y;
  const int t = threadIdx.x;
  if (role < 3) {
    const float* src = (role == 0) ? q : (role == 1) ? k : v;
    const int i = blockIdx.x * 256 + t;  // 4096*256 == (4M)/4 exactly
    float4 val = ((const float4*)src)[i];
    ushort4 o;
    o.x = f2bf(val.x); o.y = f2bf(val.y); o.z = f2bf(val.z); o.w = f2bf(val.w);
    ((ushort4*)(X + (size_t)role * 4194304))[i] = o;
  } else {
    const int z = blockIdx.x >> 10;       // 0..3
    const int tile = blockIdx.x & 1023;
    const int bx = tile & 31, by = tile >> 5;
    const float* W = (z == 0) ? Wq : (z == 1) ? Wk : (z == 2) ? Wv : Wo;
    const float sc = (z == 0) ? 0.18033688011112042f : 1.0f;  // 0.125 * log2(e)
    __shared__ u16 stile[32][33];
    const int tx = t & 31, ty = t >> 5;   // (32, 8)
    const int n0 = bx * 32, k0 = by * 32;
#pragma unroll
    for (int i = 0; i < 4; ++i)
      stile[ty + 8 * i][tx] = f2bf(W[(size_t)(k0 + ty + 8 * i) * DD + n0 + tx] * sc);
    __syncthreads();
    u16* dst = Wt + (size_t)z * 1048576;
#pragma unroll
    for (int i = 0; i < 4; ++i)
      dst[(size_t)(n0 + ty + 8 * i) * DD + k0 + tx] = stile[tx][ty + 8 * i];
  }
}

// ---------------- fused QKV GEMM: 1D grid 768, XCD-swizzled; 128x128 tile, BK=32 -----
__global__ __launch_bounds__(256, 2) void k_gemm_qkv(
    const u16* __restrict__ Xq, const u16* __restrict__ Xk, const u16* __restrict__ Xv,
    const u16* __restrict__ Wt, u16* __restrict__ Qb, u16* __restrict__ Kb,
    u16* __restrict__ Vtb) {
  const int id = blockIdx.x;
  const int rr = id & 7, t8 = id >> 3;
  const int g = (t8 >> 3) * 8 + rr, c = t8 & 7;  // g in [0,96), c in [0,8)
  const int z = g / 32, by = g % 32, bx = c;
  const u16* A = (z == 0) ? Xq : (z == 1) ? Xk : Xv;
  const u16* Bt = Wt + (size_t)z * 1048576;
  __shared__ __attribute__((aligned(16))) u16 sA[2][128 * 32];
  __shared__ __attribute__((aligned(16))) u16 sB[2][128 * 32];
  const int t = threadIdx.x;
  const int w = t >> 6, lane = t & 63;
  const int lr = lane & 15, lg = lane >> 4;
  const int wr = w >> 1, wc = w & 1;
  const int row0 = by * 128, col0 = bx * 128;

  const int srow = t >> 2;
  const int skoff = (t & 3) * 8;
  const u16* gA = A + (size_t)(row0 + srow) * DD + skoff;
  const u16* gB = Bt + (size_t)(col0 + srow) * DD + skoff;
  const int ldsbase = w * 512;

  floatx4 acc[4][4] = {};

  auto stage = [&](int buf, int kt) {
    const int ko = kt * 32;
    gload16(gA + ko, &sA[buf][ldsbase]);
    gload16(gA + ko + (size_t)64 * DD, &sA[buf][2048 + ldsbase]);
    gload16(gB + ko, &sB[buf][ldsbase]);
    gload16(gB + ko + (size_t)64 * DD, &sB[buf][2048 + ldsbase]);
  };

  int cur = 0;
  stage(0, 0);
  __syncthreads();
  for (int kt = 0; kt < 32; ++kt) {
    if (kt + 1 < 32) stage(cur ^ 1, kt + 1);
    bhalf8 af[4], bf[4];
#pragma unroll
    for (int m = 0; m < 4; ++m)
      af[m] = *(const bhalf8*)&sA[cur][(wr * 64 + m * 16 + lr) * 32 + lg * 8];
#pragma unroll
    for (int n = 0; n < 4; ++n)
      bf[n] = *(const bhalf8*)&sB[cur][(wc * 64 + n * 16 + lr) * 32 + lg * 8];
#pragma unroll
    for (int m = 0; m < 4; ++m)
#pragma unroll
      for (int n = 0; n < 4; ++n)
        acc[m][n] = __builtin_amdgcn_mfma_f32_16x16x32_bf16(af[m], bf[n], acc[m][n], 0, 0, 0);
    __syncthreads();
    cur ^= 1;
  }

#pragma unroll
  for (int m = 0; m < 4; ++m) {
#pragma unroll
    for (int n = 0; n < 4; ++n) {
      const int col = col0 + wc * 64 + n * 16 + lr;
      const int rowb = row0 + wr * 64 + m * 16 + lg * 4;
      if (z == 2) {
        // V^T layout: Vtb[(b*1024 + col)][s]
        const int bidx = rowb >> 11, s = rowb & (SS - 1);
        ushort4 pk;
        pk.x = f2bf(acc[m][n][0]); pk.y = f2bf(acc[m][n][1]);
        pk.z = f2bf(acc[m][n][2]); pk.w = f2bf(acc[m][n][3]);
        *(ushort4*)&Vtb[((size_t)bidx * 1024 + col) * SS + s] = pk;
      } else {
        u16* C = (z == 0) ? Qb : Kb;
#pragma unroll
        for (int r = 0; r < 4; ++r)
          C[(size_t)(rowb + r) * DD + col] = f2bf(acc[m][n][r]);
      }
    }
  }
}

// ---------------- Wo GEMM: 1D grid 512, XCD-swizzled; 64x128 tile, fp32 out ----------
__global__ __launch_bounds__(256, 2) void k_gemm_wo(
    const u16* __restrict__ A, const u16* __restrict__ Bt, float* __restrict__ C) {
  const int id = blockIdx.x;
  const int rr = id & 7, t8 = id >> 3;
  const int g = (t8 >> 3) * 8 + rr, c = t8 & 7;  // g in [0,64) rows, c in [0,8) cols
  const int by = g, bx = c;
  __shared__ __attribute__((aligned(16))) u16 sA[2][64 * 32];
  __shared__ __attribute__((aligned(16))) u16 sB[2][128 * 32];
  const int t = threadIdx.x;
  const int w = t >> 6, lane = t & 63;
  const int lr = lane & 15, lg = lane >> 4;
  const int wr = w >> 1, wc = w & 1;
  const int row0 = by * 64, col0 = bx * 128;

  const int srow = t >> 2;
  const int skoff = (t & 3) * 8;
  const u16* gA = A + (size_t)(row0 + srow) * DD + skoff;
  const u16* gB = Bt + (size_t)(col0 + srow) * DD + skoff;
  const int ldsbase = w * 512;

  floatx4 acc[2][4] = {};

  auto stage = [&](int buf, int kt) {
    const int ko = kt * 32;
    gload16(gA + ko, &sA[buf][ldsbase]);
    gload16(gB + ko, &sB[buf][ldsbase]);
    gload16(gB + ko + (size_t)64 * DD, &sB[buf][2048 + ldsbase]);
  };

  int cur = 0;
  stage(0, 0);
  __syncthreads();
  for (int kt = 0; kt < 32; ++kt) {
    if (kt + 1 < 32) stage(cur ^ 1, kt + 1);
    bhalf8 af[2], bf[4];
#pragma unroll
    for (int m = 0; m < 2; ++m)
      af[m] = *(const bhalf8*)&sA[cur][(wr * 32 + m * 16 + lr) * 32 + lg * 8];
#pragma unroll
    for (int n = 0; n < 4; ++n)
      bf[n] = *(const bhalf8*)&sB[cur][(wc * 64 + n * 16 + lr) * 32 + lg * 8];
#pragma unroll
    for (int m = 0; m < 2; ++m)
#pragma unroll
      for (int n = 0; n < 4; ++n)
        acc[m][n] = __builtin_amdgcn_mfma_f32_16x16x32_bf16(af[m], bf[n], acc[m][n], 0, 0, 0);
    __syncthreads();
    cur ^= 1;
  }

#pragma unroll
  for (int m = 0; m < 2; ++m)
#pragma unroll
    for (int n = 0; n < 4; ++n) {
      const int col = col0 + wc * 64 + n * 16 + lr;
      const int rowb = row0 + wr * 32 + m * 16 + lg * 4;
#pragma unroll
      for (int r = 0; r < 4; ++r)
        C[(size_t)(rowb + r) * DD + col] = acc[m][n][r];
    }
}

// ---------------- flash attention v11: 8-wave blocks (512 thr, 128 q-rows) -----------
// One 64-key K/V LDS staging shared by 8 waves (was 4) -> 2x waves/CU for the same
// LDS footprint growth of only p_lds. Per-wave inner loop identical to v10.
// grid 512*P, XCD-swizzled: 16 q-blocks of one (h,b,p) share id%8 -> same XCD.
__global__ __launch_bounds__(512, 4) void k_attn(
    const u16* __restrict__ Q, const u16* __restrict__ K, const u16* __restrict__ Vt,
    float* __restrict__ Opart, float2* __restrict__ Ml,
    const int* __restrict__ valid_lens, const int part) {
  const int id = blockIdx.x;
  const int rr = id & 7, tt = id >> 3;
  const int g = (tt >> 4) * 8 + rr, c = tt & 15;  // g = zi*16 + h
  const int h = g & 15, zi = g >> 4;
  const int b = zi & 1, p = zi >> 1;
  const int t = threadIdx.x;
  const int w = t >> 6, lane = t & 63;            // w in [0,8)
  const int lr = lane & 15, lg = lane >> 4;
  const int q0 = c * 128 + w * 16;
  const int vl = valid_lens[b];
  const int kbeg = p * part;
  if (kbeg >= vl) return;  // dead partition (uniform)
  const int kend = (vl < kbeg + part) ? vl : (kbeg + part);
  const int L = kend - kbeg;

  __shared__ __attribute__((aligned(16))) u16 kbuf[2][64 * 64];  // [key][dim] swizzled
  __shared__ __attribute__((aligned(16))) u16 vbuf[2][64 * 64];  // [d][key]  swizzled
  __shared__ __attribute__((aligned(16))) u16 p_lds[8][16 * 72]; // wave-private
  u16* pl = &p_lds[w][0];

  const u16* Qp = Q + ((size_t)(b * SS + q0 + lr)) * DD + h * DHD;
  const bhalf8 qf0 = *(const bhalf8*)(Qp + lg * 8);
  const bhalf8 qf1 = *(const bhalf8*)(Qp + 32 + lg * 8);

  // staging: wave w stages K rows w*8..w*8+7 and V rows w*8..w*8+7 (1 gload16 each).
  // per-lane source pre-swizzled so linear LDS dest ends up swizzled (rule #21).
  const int sub = lane >> 3;          // row-in-octet 0..7 (== row&7 of dest row)
  const int sc16 = (lane & 7) ^ sub;  // swizzled source col16
  const u16* ksrc = K + (size_t)(b * SS + kbeg + w * 8 + sub) * DD + h * DHD + sc16 * 8;
  const u16* vsrc = Vt + ((size_t)(b * HH + h) * DHD + w * 8 + sub) * SS + kbeg + sc16 * 8;

  auto stage = [&](int buf, int i) {
    const int sk0 = i * 64;
    gload16(ksrc + (size_t)sk0 * DD, &kbuf[buf][(w * 8) * 64]);
    gload16(vsrc + sk0,              &vbuf[buf][(w * 8) * 64]);
  };

  float mrun = -1e30f, lrun = 0.f;  // per-lane: stats of q-row (q0 + lr), log2 units
  floatx4 o[4] = {};                // o[dt]: C[q = lg*4+r][d = dt*16+lr]

  const int nblk = (L + 63) >> 6;
  const bool partial = (L & 63) != 0;
  const int swz = lr & 7;  // fragment-read swizzle (row&7 for rows c*16+lr / dt*16+lr)

  stage(0, 0);
  __syncthreads();

  int cb = 0;
  for (int i = 0; i < nblk; ++i) {
    if (i + 1 < nblk) stage(cb ^ 1, i + 1);
    const u16* kb = &kbuf[cb][0];
    const u16* vb = &vbuf[cb][0];
    // QK^T from LDS K-frags
    floatx4 s[4];
    __builtin_amdgcn_s_setprio(1);
#pragma unroll
    for (int cc = 0; cc < 4; ++cc) {
      const bhalf8 kc0 = *(const bhalf8*)&kb[(cc * 16 + lr) * 64 + ((lg ^ swz) * 8)];
      const bhalf8 kc1 = *(const bhalf8*)&kb[(cc * 16 + lr) * 64 + (((lg + 4) ^ swz) * 8)];
      floatx4 zz = {0.f, 0.f, 0.f, 0.f};
      zz = __builtin_amdgcn_mfma_f32_16x16x32_bf16(kc0, qf0, zz, 0, 0, 0);
      s[cc] = __builtin_amdgcn_mfma_f32_16x16x32_bf16(kc1, qf1, zz, 0, 0, 0);
    }
    __builtin_amdgcn_s_setprio(0);
    // mask tail keys (uniform branch; key index is per-reg)
    if (partial && i == nblk - 1) {
      const int sk0 = i * 64;
#pragma unroll
      for (int cc = 0; cc < 4; ++cc)
#pragma unroll
        for (int r = 0; r < 4; ++r)
          if (sk0 + cc * 16 + lg * 4 + r >= L) s[cc][r] = -1e6f;
    }
    // row max: in-register tree + 2 cross-lane steps
    float tmax = fmaxf(fmaxf(fmaxf(s[0][0], s[0][1]), fmaxf(s[0][2], s[0][3])),
                       fmaxf(fmaxf(s[1][0], s[1][1]), fmaxf(s[1][2], s[1][3])));
    tmax = fmaxf(tmax, fmaxf(fmaxf(fmaxf(s[2][0], s[2][1]), fmaxf(s[2][2], s[2][3])),
                             fmaxf(fmaxf(s[3][0], s[3][1]), fmaxf(s[3][2], s[3][3]))));
    tmax = fmaxf(tmax, __shfl_xor(tmax, 16));
    tmax = fmaxf(tmax, __shfl_xor(tmax, 32));
    // defer-max: skip O-rescale while max growth <= 8 (log2 units; P bounded by 256)
    if (!__all(tmax <= mrun + 8.0f)) {
      const float nm = fmaxf(mrun, tmax);
      const float sc = exp2_fast(mrun - nm);
      mrun = nm;
      lrun *= sc;
      float scb[4];
#pragma unroll
      for (int r = 0; r < 4; ++r) scb[r] = __shfl(sc, lg * 4 + r);
#pragma unroll
      for (int dt = 0; dt < 4; ++dt)
#pragma unroll
        for (int r = 0; r < 4; ++r) o[dt][r] *= scb[r];
    }
    // p = exp2(s - m), row sum, pack to bf16 pairs
    float rs = 0.f;
    u32 pk[4][2];
#pragma unroll
    for (int cc = 0; cc < 4; ++cc) {
      float p0 = exp2_fast(s[cc][0] - mrun), p1 = exp2_fast(s[cc][1] - mrun);
      float p2 = exp2_fast(s[cc][2] - mrun), p3 = exp2_fast(s[cc][3] - mrun);
      rs += (p0 + p1) + (p2 + p3);
      pk[cc][0] = cvtpk_bf16(p0, p1);
      pk[cc][1] = cvtpk_bf16(p2, p3);
    }
    rs += __shfl_xor(rs, 16);
    rs += __shfl_xor(rs, 32);
    lrun += rs;
    // P -> wave-private LDS: lane writes its own q-row (lr)
#pragma unroll
    for (int cc = 0; cc < 4; ++cc) {
      u32x2 pr; pr.x = pk[cc][0]; pr.y = pk[cc][1];
      *(u32x2*)&pl[lr * 72 + cc * 16 + lg * 4] = pr;
    }
    asm volatile("s_waitcnt lgkmcnt(0)" ::: "memory");  // in-wave write->read ordering
    const bhalf8 pa0 = *(const bhalf8*)&pl[lr * 72 + lg * 8];
    const bhalf8 pa1 = *(const bhalf8*)&pl[lr * 72 + 32 + lg * 8];
    // PV from LDS V-frags
    __builtin_amdgcn_s_setprio(1);
#pragma unroll
    for (int dt = 0; dt < 4; ++dt) {
      const bhalf8 vf0 = *(const bhalf8*)&vb[(dt * 16 + lr) * 64 + ((lg ^ swz) * 8)];
      const bhalf8 vf1 = *(const bhalf8*)&vb[(dt * 16 + lr) * 64 + (((lg + 4) ^ swz) * 8)];
      o[dt] = __builtin_amdgcn_mfma_f32_16x16x32_bf16(pa0, vf0, o[dt], 0, 0, 0);
      o[dt] = __builtin_amdgcn_mfma_f32_16x16x32_bf16(pa1, vf1, o[dt], 0, 0, 0);
    }
    __builtin_amdgcn_s_setprio(0);
    __syncthreads();  // staging of next tile drained + all waves done with cb
    cb ^= 1;
  }

  // epilogue: store unnormalized partial + (m, l)
  const size_t rowbase = ((size_t)(b * HH + h)) * SS + q0;
  const size_t pbase = (size_t)p * (BB * HH * SS);
#pragma unroll
  for (int dt = 0; dt < 4; ++dt)
#pragma unroll
    for (int r = 0; r < 4; ++r)
      Opart[(pbase + rowbase + lg * 4 + r) * DHD + dt * 16 + lr] = o[dt][r];
  if (lane < 16) {
    float2 ml; ml.x = mrun; ml.y = lrun;
    Ml[pbase + rowbase + lr] = ml;
  }
}

// ---------------- merge split-KV partials -> bf16 merged-head output -----------------
template <int P>
__global__ void k_merge(const float* __restrict__ Opart, const float2* __restrict__ Ml,
                        const int* __restrict__ valid_lens, u16* __restrict__ Ob) {
  const int t = threadIdx.x;
  const int rid = blockIdx.x * 16 + (t >> 4);  // [0, B*H*S)
  const int dc = t & 15;
  const int b = rid >> 15;
  const int h = (rid >> 11) & (HH - 1);
  const int s = rid & (SS - 1);
  const int vl = valid_lens[b];
  constexpr int part = SS / P;
  float m[P], l[P];
  float4 o4[P];
  bool live[P];
  float M = -1e30f;
#pragma unroll
  for (int p = 0; p < P; ++p) {
    live[p] = (p * part < vl);
    if (live[p]) {
      float2 ml = Ml[(size_t)p * (BB * HH * SS) + rid];
      m[p] = ml.x; l[p] = ml.y;
      o4[p] = *(const float4*)&Opart[((size_t)p * (BB * HH * SS) + rid) * DHD + dc * 4];
      M = fmaxf(M, m[p]);
    }
  }
  float L = 0.f;
  float4 acc = {0.f, 0.f, 0.f, 0.f};
#pragma unroll
  for (int p = 0; p < P; ++p)
    if (live[p]) {
      const float wgt = exp2_fast(m[p] - M);
      L += l[p] * wgt;
      acc.x += wgt * o4[p].x; acc.y += wgt * o4[p].y;
      acc.z += wgt * o4[p].z; acc.w += wgt * o4[p].w;
    }
  const float inv = 1.0f / L;
  ushort4 r;
  r.x = f2bf(acc.x * inv); r.y = f2bf(acc.y * inv);
  r.z = f2bf(acc.z * inv); r.w = f2bf(acc.w * inv);
  *(ushort4*)&Ob[((size_t)(b * SS + s)) * DD + h * DHD + dc * 4] = r;
}

extern "C" void kernel_launch(void* const* d_in, const int* in_sizes, int n_in,
                              void* d_out, int out_size, void* d_ws, size_t ws_size,
                              hipStream_t stream) {
  const float* q = (const float*)d_in[0];
  const float* k = (const float*)d_in[1];
  const float* v = (const float*)d_in[2];
  const int* vl = (const int*)d_in[3];
  const float* Wq = (const float*)d_in[4];
  const float* Wk = (const float*)d_in[5];
  const float* Wv = (const float*)d_in[6];
  const float* Wo = (const float*)d_in[7];

  char* ws = (char*)d_ws;
  u16* Xq  = (u16*)(ws + 0);          // 3 x 8 MiB bf16 inputs (dead after qkv GEMM)
  u16* Wt  = (u16*)(ws + 25165824);   // 4 x 2 MiB transposed weights
  u16* Qb  = (u16*)(ws + 33554432);   // 8 MiB each
  u16* Kb  = (u16*)(ws + 41943040);
  u16* Vtb = (u16*)(ws + 50331648);
  u16* Ob  = (u16*)(ws + 58720256);   // 8 MiB merged-head attention output

  // split-KV partials: P=2 when workspace allows; else P=1 overlaying dead Xq
  const bool big = ws_size >= (size_t)134 * 1024 * 1024;
  const int P = big ? 2 : 1;
  const int part = SS / P;
  float* Opart = big ? (float*)(ws + 67108864) : (float*)(ws + 0);
  float2* Ml   = big ? (float2*)(ws + 100663296) : (float2*)(ws + 16777216);

  k_prep<<<dim3(4096, 4), 256, 0, stream>>>(q, k, v, Wq, Wk, Wv, Wo, Xq, Wt);
  k_gemm_qkv<<<768, 256, 0, stream>>>(Xq, Xq + 4194304, Xq + 8388608, Wt, Qb, Kb, Vtb);
  k_attn<<<512 * P, 512, 0, stream>>>(Qb, Kb, Vtb, Opart, Ml, vl, part);
  if (big) k_merge<2><<<4096, 256, 0, stream>>>(Opart, Ml, vl, Ob);
  else     k_merge<1><<<4096, 256, 0, stream>>>(Opart, Ml, vl, Ob);
  u16* Wto = Wt + 3 * 1048576;
  k_gemm_wo<<<512, 256, 0, stream>>>(Ob, Wto, (float*)d_out);
}